// Round 5
// baseline (180.798 us; speedup 1.0000x reference)
//
#include <hip/hip_runtime.h>
#include <hip/hip_bf16.h>

typedef __bf16 bf16;
typedef __bf16 bf16x4 __attribute__((ext_vector_type(4)));
typedef __bf16 bf16x8 __attribute__((ext_vector_type(8)));
typedef float f32x4 __attribute__((ext_vector_type(4)));
typedef float f32x16 __attribute__((ext_vector_type(16)));
typedef unsigned int u32x4 __attribute__((ext_vector_type(4)));

#define NH 16
#define HD 64
#define SEQ 2048
#define DM 1024
#define MTOT 4096   // B*S

__device__ __forceinline__ void gload_lds16(const void* g, void* l) {
  __builtin_amdgcn_global_load_lds(
      (const __attribute__((address_space(1))) void*)g,
      (__attribute__((address_space(3))) void*)l, 16, 0, 0);
}

// ---------------- fp32 -> bf16 conversion (vectorized) ----------------
__global__ void cvt_kernel(const float* __restrict__ in, bf16* __restrict__ out, int n4) {
  int i = blockIdx.x * blockDim.x + threadIdx.x;
  if (i >= n4) return;
  float4 v = reinterpret_cast<const float4*>(in)[i];
  bf16x4 o;
  o[0] = (bf16)v.x; o[1] = (bf16)v.y; o[2] = (bf16)v.z; o[3] = (bf16)v.w;
  *reinterpret_cast<bf16x4*>(out + (size_t)i * 4) = o;
}

// 4 weight matrices (1M elems each) -> contiguous bf16 out
__global__ void cvt4_kernel(const float* __restrict__ w0, const float* __restrict__ w1,
                            const float* __restrict__ w2, const float* __restrict__ w3,
                            bf16* __restrict__ out) {
  int i = blockIdx.x * blockDim.x + threadIdx.x;   // 0 .. 4*262144-1
  int seg = i >> 18;
  int j = i & 262143;
  const float* src = seg == 0 ? w0 : seg == 1 ? w1 : seg == 2 ? w2 : w3;
  float4 v = reinterpret_cast<const float4*>(src)[j];
  bf16x4 o;
  o[0] = (bf16)v.x; o[1] = (bf16)v.y; o[2] = (bf16)v.z; o[3] = (bf16)v.w;
  *reinterpret_cast<bf16x4*>(out + ((size_t)seg << 20) + (size_t)j * 4) = o;
}

// ---------------- RoPE cos/sin table: tab[m][i2] = (cos, sin) ----------------
__global__ void rope_tab_kernel(const int* __restrict__ pos, float2* __restrict__ tab) {
  int i = blockIdx.x * blockDim.x + threadIdx.x;
  if (i >= MTOT * 32) return;
  int m = i >> 5, i2 = i & 31;
  float pf = (float)pos[m];
  float inv = 1.0f / powf(10000.0f, (float)(2 * i2) * (1.0f / 64.0f));
  float a = pf * inv;
  tab[i] = make_float2(cosf(a), sinf(a));
}

// ---------------- fused QKV projection GEMM ----------------
// blockIdx.x in 0..23: proj = x>>3 (0=Q,1=K,2=V), n0 = (x&7)*128.
// Q: RoPE + 0.125*log2e scale (attn works in exp2 domain) -> [B,H,S,hd]
// K: RoPE -> [B,H,S,hd]; V: -> [B,H,hd,S]
__global__ __launch_bounds__(256) void gemm_qkv(
    const bf16* __restrict__ A, const bf16* __restrict__ wq,
    const bf16* __restrict__ wk, const bf16* __restrict__ wv,
    bf16* __restrict__ outq, bf16* __restrict__ outk, bf16* __restrict__ outv,
    const float2* __restrict__ tab)
{
  __shared__ bf16 As[128 * 32];
  __shared__ bf16 Bs[128 * 32];
  const int t = threadIdx.x;
  const int w = t >> 6;
  const int lane = t & 63;
  const int lr = lane & 15;
  const int lg = lane >> 4;
  const int lk = lg << 3;
  const int m0 = blockIdx.y * 128;
  const int proj = blockIdx.x >> 3;
  const int n0 = (blockIdx.x & 7) * 128;
  const bf16* Bw = proj == 0 ? wq : proj == 1 ? wk : wv;
  const int wr = w >> 1, wc = w & 1;

  f32x4 acc[4][4] = {};

  for (int k0 = 0; k0 < DM; k0 += 32) {
#pragma unroll
    for (int pp = 0; pp < 2; ++pp) {
      int chunk = pp * 256 + t;
      int r = chunk >> 2;
      int c = (chunk & 3) << 3;
      gload_lds16(A + (size_t)(m0 + r) * DM + k0 + c, (char*)As + (pp * 256 + w * 64) * 16);
      gload_lds16(Bw + (size_t)(n0 + r) * DM + k0 + c, (char*)Bs + (pp * 256 + w * 64) * 16);
    }
    __syncthreads();
    bf16x8 af[4], bfr[4];
#pragma unroll
    for (int f = 0; f < 4; ++f) {
      af[f]  = *reinterpret_cast<const bf16x8*>(As + (wr * 64 + f * 16 + lr) * 32 + lk);
      bfr[f] = *reinterpret_cast<const bf16x8*>(Bs + (wc * 64 + f * 16 + lr) * 32 + lk);
    }
#pragma unroll
    for (int i = 0; i < 4; ++i)
#pragma unroll
      for (int j = 0; j < 4; ++j)
        acc[i][j] = __builtin_amdgcn_mfma_f32_16x16x32_bf16(af[i], bfr[j], acc[i][j], 0, 0, 0);
    __syncthreads();
  }

  if (proj < 2) {
    bf16* outb = proj ? outk : outq;
#pragma unroll
    for (int j = 0; j < 4; ++j) {
      int n = n0 + wc * 64 + j * 16 + lr;
      int h = n >> 6, d = n & 63;
      int i2 = d >> 1;
      bool odd = d & 1;
#pragma unroll
      for (int i = 0; i < 4; ++i) {
#pragma unroll
        for (int rr = 0; rr < 4; ++rr) {
          int m = m0 + wr * 64 + i * 16 + lg * 4 + rr;
          float v = acc[i][j][rr];
          float o = __shfl_xor(v, 1);
          float2 cs = tab[(m << 5) + i2];
          float res = odd ? (v * cs.x + o * cs.y) : (v * cs.x - o * cs.y);
          if (proj == 0) res *= 0.125f * 1.44269504f;   // 1/sqrt(hd) * log2(e)
          outb[((size_t)((m >> 11) * NH + h) * SEQ + (m & 2047)) * HD + d] = (bf16)res;
        }
      }
    }
  } else {
#pragma unroll
    for (int j = 0; j < 4; ++j) {
      int n = n0 + wc * 64 + j * 16 + lr;
      int h = n >> 6, d = n & 63;
#pragma unroll
      for (int i = 0; i < 4; ++i) {
#pragma unroll
        for (int rr = 0; rr < 4; ++rr) {
          int m = m0 + wr * 64 + i * 16 + lg * 4 + rr;
          outv[((size_t)((m >> 11) * NH + h) * HD + d) * SEQ + (m & 2047)] = (bf16)acc[i][j][rr];
        }
      }
    }
  }
}

// ---------------- output projection GEMM (A from att [B,H,S,hd]) ----------------
__global__ __launch_bounds__(256) void gemm_out(
    const bf16* __restrict__ A, const bf16* __restrict__ Bw, float* __restrict__ outf)
{
  __shared__ bf16 As[128 * 32];
  __shared__ bf16 Bs[128 * 32];
  const int t = threadIdx.x;
  const int w = t >> 6;
  const int lane = t & 63;
  const int lr = lane & 15;
  const int lg = lane >> 4;
  const int lk = lg << 3;
  const int m0 = blockIdx.y * 128;
  const int n0 = blockIdx.x * 128;
  const int wr = w >> 1, wc = w & 1;

  f32x4 acc[4][4] = {};

  for (int k0 = 0; k0 < DM; k0 += 32) {
#pragma unroll
    for (int pp = 0; pp < 2; ++pp) {
      int chunk = pp * 256 + t;
      int r = chunk >> 2;
      int c = (chunk & 3) << 3;
      int m = m0 + r;
      int kk = k0 + c;
      const bf16* ga = A + (((size_t)((m >> 11) * NH + (kk >> 6)) * SEQ + (m & 2047)) * HD + (kk & 63));
      gload_lds16(ga, (char*)As + (pp * 256 + w * 64) * 16);
      gload_lds16(Bw + (size_t)(n0 + r) * DM + k0 + c, (char*)Bs + (pp * 256 + w * 64) * 16);
    }
    __syncthreads();
    bf16x8 af[4], bfr[4];
#pragma unroll
    for (int f = 0; f < 4; ++f) {
      af[f]  = *reinterpret_cast<const bf16x8*>(As + (wr * 64 + f * 16 + lr) * 32 + lk);
      bfr[f] = *reinterpret_cast<const bf16x8*>(Bs + (wc * 64 + f * 16 + lr) * 32 + lk);
    }
#pragma unroll
    for (int i = 0; i < 4; ++i)
#pragma unroll
      for (int j = 0; j < 4; ++j)
        acc[i][j] = __builtin_amdgcn_mfma_f32_16x16x32_bf16(af[i], bfr[j], acc[i][j], 0, 0, 0);
    __syncthreads();
  }

#pragma unroll
  for (int j = 0; j < 4; ++j) {
    int n = n0 + wc * 64 + j * 16 + lr;
#pragma unroll
    for (int i = 0; i < 4; ++i) {
#pragma unroll
      for (int rr = 0; rr < 4; ++rr) {
        int m = m0 + wr * 64 + i * 16 + lg * 4 + rr;
        outf[(size_t)m * DM + n] = acc[i][j][rr];
      }
    }
  }
}

// ---------------- flash attention ----------------
// 512 blocks x 256 threads. Block covers strips 2j (waves 0,1), 2j+1 (waves 2,3).
// K staged in a 6-buffer LDS ring (3 tile-pairs deep), ONE barrier per pair,
// counted vmcnt keeps next pair's loads in flight. V read direct from global
// (L2/L1-resident), issued right after QK so softmax hides the latency.
__device__ __forceinline__ void stage_tile(const char* gRow0, size_t rowStrideB, int colByte0,
                                           char* lds, int t) {
#pragma unroll
  for (int p = 0; p < 2; ++p) {
    int o = (p * 256 + t) * 16;
    int r = o >> 7;
    int cb = o & 127;
    int cbs = cb ^ ((r & 7) << 4);
    gload_lds16(gRow0 + (size_t)r * rowStrideB + colByte0 + cbs, lds + o);
  }
}

__device__ __forceinline__ bf16x8 frag64(const char* tile, int row, int colByte) {
  int b = row * 128 + (colByte ^ ((row & 7) << 4));
  return *reinterpret_cast<const bf16x8*>(tile + b);
}

__device__ __forceinline__ unsigned packw(float a, float b) {
  unsigned short la = __builtin_bit_cast(unsigned short, (bf16)a);
  unsigned short lb = __builtin_bit_cast(unsigned short, (bf16)b);
  return (unsigned)la | ((unsigned)lb << 16);
}

__device__ __forceinline__ void qk_tile(const char* Kt, const bf16x8* qf,
                                        f32x16& s0, f32x16& s1, int l31, int h) {
  s0 = (f32x16){};
  s1 = (f32x16){};
  __builtin_amdgcn_s_setprio(1);
#pragma unroll
  for (int s = 0; s < 4; ++s) {
    bf16x8 kf0 = frag64(Kt, l31, s * 32 + h * 16);
    bf16x8 kf1 = frag64(Kt, 32 + l31, s * 32 + h * 16);
    s0 = __builtin_amdgcn_mfma_f32_32x32x16_bf16(kf0, qf[s], s0, 0, 0, 0);
    s1 = __builtin_amdgcn_mfma_f32_32x32x16_bf16(kf1, qf[s], s1, 0, 0, 0);
  }
  __builtin_amdgcn_s_setprio(0);
}

__device__ __forceinline__ void sm_pv(f32x16& s0, f32x16& s1,
                                      const bf16x8* v0, const bf16x8* v1,
                                      f32x16& acc0, f32x16& acc1,
                                      float& mrow, float& lrow,
                                      int l31, int h, bool domask, int qloc) {
  if (domask) {
#pragma unroll
    for (int reg = 0; reg < 16; ++reg) {
      int ro = (reg & 3) + 8 * (reg >> 2) + 4 * h;
      if (ro > qloc) s0[reg] = -1e30f;
      if (ro + 32 > qloc) s1[reg] = -1e30f;
    }
  }
  // max (defer-rescale T13), log2 domain
  float tm[16];
#pragma unroll
  for (int i = 0; i < 16; ++i) tm[i] = fmaxf(s0[i], s1[i]);
#pragma unroll
  for (int off = 8; off >= 1; off >>= 1)
#pragma unroll
    for (int i = 0; i < off; ++i) tm[i] = fmaxf(tm[i], tm[i + off]);
  float rmax = fmaxf(tm[0], __shfl_xor(tm[0], 32));
  bool need = __any(rmax > mrow + 11.5f);
  if (need) {
    float mnew = fmaxf(mrow, rmax);
    float osc = exp2f(mrow - mnew);
#pragma unroll
    for (int reg = 0; reg < 16; ++reg) {
      int rs = (reg & 3) + 8 * (reg >> 2) + 4 * h;
      float o = __shfl(osc, rs);
      acc0[reg] *= o;
      acc1[reg] *= o;
    }
    lrow *= osc;
    mrow = mnew;
  }
#pragma unroll
  for (int i = 0; i < 16; ++i) {
    s0[i] = exp2f(s0[i] - mrow);
    s1[i] = exp2f(s1[i] - mrow);
  }
  float ts[16];
#pragma unroll
  for (int i = 0; i < 16; ++i) ts[i] = s0[i] + s1[i];
#pragma unroll
  for (int off = 8; off >= 1; off >>= 1)
#pragma unroll
    for (int i = 0; i < off; ++i) ts[i] += ts[i + off];
  lrow += ts[0] + __shfl_xor(ts[0], 32);

  // in-register P -> A-fragment repack
  unsigned W0[4][2], W1[4][2], X0[4][2], X1[4][2];
#pragma unroll
  for (int sp = 0; sp < 4; ++sp)
#pragma unroll
    for (int u = 0; u < 2; ++u) {
      W0[sp][u] = packw(s0[sp * 4 + 2 * u], s0[sp * 4 + 2 * u + 1]);
      W1[sp][u] = packw(s1[sp * 4 + 2 * u], s1[sp * 4 + 2 * u + 1]);
    }
#pragma unroll
  for (int sp = 0; sp < 4; ++sp)
#pragma unroll
    for (int u = 0; u < 2; ++u) {
      X0[sp][u] = (unsigned)__shfl_xor((int)W0[sp][u], 32);
      X1[sp][u] = (unsigned)__shfl_xor((int)W1[sp][u], 32);
    }
  // PV
  __builtin_amdgcn_s_setprio(1);
#pragma unroll
  for (int ks = 0; ks < 4; ++ks) {
    const unsigned (*W)[2] = (ks < 2) ? W0 : W1;
    const unsigned (*X)[2] = (ks < 2) ? X0 : X1;
    const int c = ks & 1;
    unsigned m0 = h ? X[2 * c + 1][0] : W[2 * c][0];
    unsigned m1 = h ? X[2 * c + 1][1] : W[2 * c][1];
    unsigned m2 = h ? W[2 * c + 1][0] : X[2 * c][0];
    unsigned m3 = h ? W[2 * c + 1][1] : X[2 * c][1];
    u32x4 pw = {m0, m1, m2, m3};
    bf16x8 pf = __builtin_bit_cast(bf16x8, pw);
    acc0 = __builtin_amdgcn_mfma_f32_32x32x16_bf16(pf, v0[ks], acc0, 0, 0, 0);
    acc1 = __builtin_amdgcn_mfma_f32_32x32x16_bf16(pf, v1[ks], acc1, 0, 0, 0);
  }
  __builtin_amdgcn_s_setprio(0);
}

__global__ __launch_bounds__(256) void attn_kernel(
    const bf16* __restrict__ q, const bf16* __restrict__ k,
    const bf16* __restrict__ vt, bf16* __restrict__ att)
{
  __shared__ bf16 Ks[6][64 * 64];
  const int t = threadIdx.x;
  const int w = t >> 6;
  const int lane = t & 63;
  const int l31 = lane & 31;
  const int h = lane >> 5;

  // decode (j, bh) with complementary pairing: blocks idx and idx+256 sum to const work
  const int idx = blockIdx.x;
  const int half = idx >> 8;
  const int sub = idx & 255;
  const int bh = sub & 31;
  const int j = half ? (sub >> 5) : (15 - (sub >> 5));

  const int strip = 2 * j + (w >> 1);      // this wave's 64-row strip
  const int myN = strip + 1;               // kv tiles this wave computes
  const int npair = j + 1;                 // tile-pairs staged by the block
  const int q0w = j * 128 + w * 32;        // this wave's 32 q-rows
  const int qloc = (w & 1) * 32 + l31;     // row within strip

  const bf16* qb = q + (size_t)bh * SEQ * HD;
  const char* kbB = (const char*)(k + (size_t)bh * SEQ * HD);
  const char* vbB = (const char*)(vt + (size_t)bh * HD * SEQ);

  // Q fragments (B operand of 32x32x16)
  bf16x8 qf[4];
#pragma unroll
  for (int s = 0; s < 4; ++s)
    qf[s] = *reinterpret_cast<const bf16x8*>(qb + (size_t)(q0w + l31) * HD + s * 16 + h * 8);

  f32x16 acc0 = {}, acc1 = {};
  float mrow = -1e30f, lrow = 0.f;

  // prologue: stage pairs 0 and 1
  stage_tile(kbB, 128, 0, (char*)Ks[0], t);
  stage_tile(kbB + 8192, 128, 0, (char*)Ks[1], t);
  if (npair > 1) {
    stage_tile(kbB + 2 * 8192, 128, 0, (char*)Ks[2], t);
    stage_tile(kbB + 3 * 8192, 128, 0, (char*)Ks[3], t);
    asm volatile("s_waitcnt vmcnt(4)" ::: "memory");   // pair 0 arrived
  } else {
    asm volatile("s_waitcnt vmcnt(0)" ::: "memory");
  }

  for (int u = 0; u < npair; ++u) {
    __builtin_amdgcn_s_barrier();   // pair u arrived everywhere; pair u-1 consumed
    if (u + 2 < npair) {
      int tt = 2 * u + 4;
      stage_tile(kbB + (size_t)tt * 8192, 128, 0, (char*)Ks[tt % 6], t);
      stage_tile(kbB + (size_t)(tt + 1) * 8192, 128, 0, (char*)Ks[(tt + 1) % 6], t);
      asm volatile("s_waitcnt vmcnt(4)" ::: "memory"); // pair u+1 arrived (locally)
    } else {
      asm volatile("s_waitcnt vmcnt(0)" ::: "memory");
    }
    __builtin_amdgcn_sched_barrier(0);

    const int t0 = 2 * u, t1 = 2 * u + 1;
    const char* K0 = (const char*)Ks[(2 * u) % 6];
    const char* K1 = (const char*)Ks[(2 * u + 1) % 6];
    const bool do1 = (t1 < myN);

    // QK for both tiles + early V loads (latency hidden under softmax)
    f32x16 p0a, p0b, p1a, p1b;
    qk_tile(K0, qf, p0a, p0b, l31, h);
    bf16x8 va0[4], vb0[4], va1[4], vb1[4];
#pragma unroll
    for (int ks = 0; ks < 4; ++ks) {
      va0[ks] = *reinterpret_cast<const bf16x8*>(vbB + (size_t)l31 * 4096 + t0 * 128 + ks * 32 + h * 16);
      vb0[ks] = *reinterpret_cast<const bf16x8*>(vbB + (size_t)(32 + l31) * 4096 + t0 * 128 + ks * 32 + h * 16);
    }
    if (do1) {
      qk_tile(K1, qf, p1a, p1b, l31, h);
#pragma unroll
      for (int ks = 0; ks < 4; ++ks) {
        va1[ks] = *reinterpret_cast<const bf16x8*>(vbB + (size_t)l31 * 4096 + t1 * 128 + ks * 32 + h * 16);
        vb1[ks] = *reinterpret_cast<const bf16x8*>(vbB + (size_t)(32 + l31) * 4096 + t1 * 128 + ks * 32 + h * 16);
      }
    }
    sm_pv(p0a, p0b, va0, vb0, acc0, acc1, mrow, lrow, l31, h, t0 == strip, qloc);
    if (do1)
      sm_pv(p1a, p1b, va1, vb1, acc0, acc1, mrow, lrow, l31, h, t1 == strip, qloc);
  }

  // ---- normalize + write: O[q0w + row][d], row = (reg&3)+8*(reg>>2)+4h ----
#pragma unroll
  for (int reg = 0; reg < 16; ++reg) {
    int rs = (reg & 3) + 8 * (reg >> 2) + 4 * h;
    float li = __shfl(lrow, rs);
    size_t base = ((size_t)bh * SEQ + q0w + rs) * HD;
    att[base + l31]      = (bf16)(acc0[reg] / li);
    att[base + 32 + l31] = (bf16)(acc1[reg] / li);
  }
}

extern "C" void kernel_launch(void* const* d_in, const int* in_sizes, int n_in,
                              void* d_out, int out_size, void* d_ws, size_t ws_size,
                              hipStream_t stream) {
  const float* x  = (const float*)d_in[0];
  const int* pos  = (const int*)d_in[1];
  const float* Wq = (const float*)d_in[2];
  const float* Wk = (const float*)d_in[3];
  const float* Wv = (const float*)d_in[4];
  const float* Wo = (const float*)d_in[5];
  float* out = (float*)d_out;

  char* p = (char*)d_ws;
  bf16* xb   = (bf16*)p; p += (size_t)MTOT * DM * 2;
  bf16* wqb  = (bf16*)p; p += (size_t)DM * DM * 2;
  bf16* wkb  = (bf16*)p; p += (size_t)DM * DM * 2;
  bf16* wvb  = (bf16*)p; p += (size_t)DM * DM * 2;
  bf16* wob  = (bf16*)p; p += (size_t)DM * DM * 2;
  bf16* qb   = (bf16*)p; p += (size_t)MTOT * DM * 2;
  bf16* kb   = (bf16*)p; p += (size_t)MTOT * DM * 2;
  bf16* vtb  = (bf16*)p; p += (size_t)MTOT * DM * 2;
  bf16* attb = (bf16*)p; p += (size_t)MTOT * DM * 2;
  float2* tab = (float2*)p; p += (size_t)MTOT * 32 * sizeof(float2);

  cvt_kernel<<<(MTOT * DM / 4 + 255) / 256, 256, 0, stream>>>(x, xb, MTOT * DM / 4);
  cvt4_kernel<<<(4 * 262144 + 255) / 256, 256, 0, stream>>>(Wq, Wk, Wv, Wo, wqb);
  rope_tab_kernel<<<(MTOT * 32 + 255) / 256, 256, 0, stream>>>(pos, tab);

  gemm_qkv<<<dim3(24, MTOT / 128), 256, 0, stream>>>(xb, wqb, wkb, wvb, qb, kb, vtb, tab);

  attn_kernel<<<512, 256, 0, stream>>>(qb, kb, vtb, attb);

  gemm_out<<<dim3(DM / 128, MTOT / 128), 256, 0, stream>>>(attb, wob, out);
}

// Round 6
// 156.183 us; speedup vs baseline: 1.1576x; 1.1576x over previous
//
#include <hip/hip_runtime.h>
#include <hip/hip_bf16.h>

typedef __bf16 bf16;
typedef __bf16 bf16x4 __attribute__((ext_vector_type(4)));
typedef __bf16 bf16x8 __attribute__((ext_vector_type(8)));
typedef float f32x4 __attribute__((ext_vector_type(4)));
typedef float f32x16 __attribute__((ext_vector_type(16)));
typedef unsigned int u32x4 __attribute__((ext_vector_type(4)));

#define NH 16
#define HD 64
#define SEQ 2048
#define DM 1024
#define MTOT 4096   // B*S

__device__ __forceinline__ void gload_lds16(const void* g, void* l) {
  __builtin_amdgcn_global_load_lds(
      (const __attribute__((address_space(1))) void*)g,
      (__attribute__((address_space(3))) void*)l, 16, 0, 0);
}

// ---------------- fp32 -> bf16 conversion (vectorized) ----------------
__global__ void cvt_kernel(const float* __restrict__ in, bf16* __restrict__ out, int n4) {
  int i = blockIdx.x * blockDim.x + threadIdx.x;
  if (i >= n4) return;
  float4 v = reinterpret_cast<const float4*>(in)[i];
  bf16x4 o;
  o[0] = (bf16)v.x; o[1] = (bf16)v.y; o[2] = (bf16)v.z; o[3] = (bf16)v.w;
  *reinterpret_cast<bf16x4*>(out + (size_t)i * 4) = o;
}

// 4 weight matrices (1M elems each) -> contiguous bf16 out
__global__ void cvt4_kernel(const float* __restrict__ w0, const float* __restrict__ w1,
                            const float* __restrict__ w2, const float* __restrict__ w3,
                            bf16* __restrict__ out) {
  int i = blockIdx.x * blockDim.x + threadIdx.x;   // 0 .. 4*262144-1
  int seg = i >> 18;
  int j = i & 262143;
  const float* src = seg == 0 ? w0 : seg == 1 ? w1 : seg == 2 ? w2 : w3;
  float4 v = reinterpret_cast<const float4*>(src)[j];
  bf16x4 o;
  o[0] = (bf16)v.x; o[1] = (bf16)v.y; o[2] = (bf16)v.z; o[3] = (bf16)v.w;
  *reinterpret_cast<bf16x4*>(out + ((size_t)seg << 20) + (size_t)j * 4) = o;
}

// ---------------- RoPE cos/sin table: tab[m][i2] = (cos, sin) ----------------
__global__ void rope_tab_kernel(const int* __restrict__ pos, float2* __restrict__ tab) {
  int i = blockIdx.x * blockDim.x + threadIdx.x;
  if (i >= MTOT * 32) return;
  int m = i >> 5, i2 = i & 31;
  float pf = (float)pos[m];
  float inv = 1.0f / powf(10000.0f, (float)(2 * i2) * (1.0f / 64.0f));
  float a = pf * inv;
  tab[i] = make_float2(cosf(a), sinf(a));
}

// ---------------- fused QKV projection GEMM ----------------
// blockIdx.x in 0..23: proj = x>>3 (0=Q,1=K,2=V), n0 = (x&7)*128.
// Q: RoPE + 0.125*log2e scale (attn works in exp2 domain) -> [B,H,S,hd]
// K: RoPE -> [B,H,S,hd]; V: -> [B,H,hd,S]
__global__ __launch_bounds__(256) void gemm_qkv(
    const bf16* __restrict__ A, const bf16* __restrict__ wq,
    const bf16* __restrict__ wk, const bf16* __restrict__ wv,
    bf16* __restrict__ outq, bf16* __restrict__ outk, bf16* __restrict__ outv,
    const float2* __restrict__ tab)
{
  __shared__ bf16 As[128 * 32];
  __shared__ bf16 Bs[128 * 32];
  const int t = threadIdx.x;
  const int w = t >> 6;
  const int lane = t & 63;
  const int lr = lane & 15;
  const int lg = lane >> 4;
  const int lk = lg << 3;
  const int m0 = blockIdx.y * 128;
  const int proj = blockIdx.x >> 3;
  const int n0 = (blockIdx.x & 7) * 128;
  const bf16* Bw = proj == 0 ? wq : proj == 1 ? wk : wv;
  const int wr = w >> 1, wc = w & 1;

  f32x4 acc[4][4] = {};

  for (int k0 = 0; k0 < DM; k0 += 32) {
#pragma unroll
    for (int pp = 0; pp < 2; ++pp) {
      int chunk = pp * 256 + t;
      int r = chunk >> 2;
      int c = (chunk & 3) << 3;
      gload_lds16(A + (size_t)(m0 + r) * DM + k0 + c, (char*)As + (pp * 256 + w * 64) * 16);
      gload_lds16(Bw + (size_t)(n0 + r) * DM + k0 + c, (char*)Bs + (pp * 256 + w * 64) * 16);
    }
    __syncthreads();
    bf16x8 af[4], bfr[4];
#pragma unroll
    for (int f = 0; f < 4; ++f) {
      af[f]  = *reinterpret_cast<const bf16x8*>(As + (wr * 64 + f * 16 + lr) * 32 + lk);
      bfr[f] = *reinterpret_cast<const bf16x8*>(Bs + (wc * 64 + f * 16 + lr) * 32 + lk);
    }
#pragma unroll
    for (int i = 0; i < 4; ++i)
#pragma unroll
      for (int j = 0; j < 4; ++j)
        acc[i][j] = __builtin_amdgcn_mfma_f32_16x16x32_bf16(af[i], bfr[j], acc[i][j], 0, 0, 0);
    __syncthreads();
  }

  if (proj < 2) {
    bf16* outb = proj ? outk : outq;
#pragma unroll
    for (int j = 0; j < 4; ++j) {
      int n = n0 + wc * 64 + j * 16 + lr;
      int h = n >> 6, d = n & 63;
      int i2 = d >> 1;
      bool odd = d & 1;
#pragma unroll
      for (int i = 0; i < 4; ++i) {
#pragma unroll
        for (int rr = 0; rr < 4; ++rr) {
          int m = m0 + wr * 64 + i * 16 + lg * 4 + rr;
          float v = acc[i][j][rr];
          float o = __shfl_xor(v, 1);
          float2 cs = tab[(m << 5) + i2];
          float res = odd ? (v * cs.x + o * cs.y) : (v * cs.x - o * cs.y);
          if (proj == 0) res *= 0.125f * 1.44269504f;   // 1/sqrt(hd) * log2(e)
          outb[((size_t)((m >> 11) * NH + h) * SEQ + (m & 2047)) * HD + d] = (bf16)res;
        }
      }
    }
  } else {
#pragma unroll
    for (int j = 0; j < 4; ++j) {
      int n = n0 + wc * 64 + j * 16 + lr;
      int h = n >> 6, d = n & 63;
#pragma unroll
      for (int i = 0; i < 4; ++i) {
#pragma unroll
        for (int rr = 0; rr < 4; ++rr) {
          int m = m0 + wr * 64 + i * 16 + lg * 4 + rr;
          outv[((size_t)((m >> 11) * NH + h) * HD + d) * SEQ + (m & 2047)] = (bf16)acc[i][j][rr];
        }
      }
    }
  }
}

// ---------------- output projection GEMM (A from att [B,H,S,hd]) ----------------
__global__ __launch_bounds__(256) void gemm_out(
    const bf16* __restrict__ A, const bf16* __restrict__ Bw, float* __restrict__ outf)
{
  __shared__ bf16 As[128 * 32];
  __shared__ bf16 Bs[128 * 32];
  const int t = threadIdx.x;
  const int w = t >> 6;
  const int lane = t & 63;
  const int lr = lane & 15;
  const int lg = lane >> 4;
  const int lk = lg << 3;
  const int m0 = blockIdx.y * 128;
  const int n0 = blockIdx.x * 128;
  const int wr = w >> 1, wc = w & 1;

  f32x4 acc[4][4] = {};

  for (int k0 = 0; k0 < DM; k0 += 32) {
#pragma unroll
    for (int pp = 0; pp < 2; ++pp) {
      int chunk = pp * 256 + t;
      int r = chunk >> 2;
      int c = (chunk & 3) << 3;
      int m = m0 + r;
      int kk = k0 + c;
      const bf16* ga = A + (((size_t)((m >> 11) * NH + (kk >> 6)) * SEQ + (m & 2047)) * HD + (kk & 63));
      gload_lds16(ga, (char*)As + (pp * 256 + w * 64) * 16);
      gload_lds16(Bw + (size_t)(n0 + r) * DM + k0 + c, (char*)Bs + (pp * 256 + w * 64) * 16);
    }
    __syncthreads();
    bf16x8 af[4], bfr[4];
#pragma unroll
    for (int f = 0; f < 4; ++f) {
      af[f]  = *reinterpret_cast<const bf16x8*>(As + (wr * 64 + f * 16 + lr) * 32 + lk);
      bfr[f] = *reinterpret_cast<const bf16x8*>(Bs + (wc * 64 + f * 16 + lr) * 32 + lk);
    }
#pragma unroll
    for (int i = 0; i < 4; ++i)
#pragma unroll
      for (int j = 0; j < 4; ++j)
        acc[i][j] = __builtin_amdgcn_mfma_f32_16x16x32_bf16(af[i], bfr[j], acc[i][j], 0, 0, 0);
    __syncthreads();
  }

#pragma unroll
  for (int j = 0; j < 4; ++j) {
    int n = n0 + wc * 64 + j * 16 + lr;
#pragma unroll
    for (int i = 0; i < 4; ++i) {
#pragma unroll
      for (int rr = 0; rr < 4; ++rr) {
        int m = m0 + wr * 64 + i * 16 + lg * 4 + rr;
        outf[(size_t)m * DM + n] = acc[i][j][rr];
      }
    }
  }
}

// ---------------- flash attention ----------------
// 512 blocks x 256 threads. Block covers strips 2j (waves 0,1), 2j+1 (waves 2,3).
// K and V both LDS-staged (coalesced gload_lds, swizzled). Ring of 2 tile-PAIRS
// (Ks[4]+Vs[4] = 64 KB). One barrier-pair per tile-pair: vmcnt(8) certifies the
// current pair while the next pair's 8 loads stay in flight; stage of pair u+2
// sits after the barrier proving all waves finished pair u (its slots).
__device__ __forceinline__ void stage_tile(const char* gRow0, size_t rowStrideB, int colByte0,
                                           char* lds, int t) {
#pragma unroll
  for (int p = 0; p < 2; ++p) {
    int o = (p * 256 + t) * 16;
    int r = o >> 7;
    int cb = o & 127;
    int cbs = cb ^ ((r & 7) << 4);
    gload_lds16(gRow0 + (size_t)r * rowStrideB + colByte0 + cbs, lds + o);
  }
}

__device__ __forceinline__ bf16x8 frag64(const char* tile, int row, int colByte) {
  int b = row * 128 + (colByte ^ ((row & 7) << 4));
  return *reinterpret_cast<const bf16x8*>(tile + b);
}

__device__ __forceinline__ unsigned packw(float a, float b) {
  unsigned short la = __builtin_bit_cast(unsigned short, (bf16)a);
  unsigned short lb = __builtin_bit_cast(unsigned short, (bf16)b);
  return (unsigned)la | ((unsigned)lb << 16);
}

// one kv-tile: QK^T (swapped operands), online softmax, in-register repack, PV
__device__ __forceinline__ void tile_step(const char* Kt, const char* Vt,
                                          const bf16x8* qf,
                                          f32x16& acc0, f32x16& acc1,
                                          float& mrow, float& lrow,
                                          int l31, int h, bool domask, int qloc) {
  f32x16 s0 = {}, s1 = {};
  __builtin_amdgcn_s_setprio(1);
#pragma unroll
  for (int s = 0; s < 4; ++s) {
    bf16x8 kf0 = frag64(Kt, l31, s * 32 + h * 16);
    bf16x8 kf1 = frag64(Kt, 32 + l31, s * 32 + h * 16);
    s0 = __builtin_amdgcn_mfma_f32_32x32x16_bf16(kf0, qf[s], s0, 0, 0, 0);
    s1 = __builtin_amdgcn_mfma_f32_32x32x16_bf16(kf1, qf[s], s1, 0, 0, 0);
  }
  __builtin_amdgcn_s_setprio(0);
  if (domask) {
#pragma unroll
    for (int reg = 0; reg < 16; ++reg) {
      int ro = (reg & 3) + 8 * (reg >> 2) + 4 * h;
      if (ro > qloc) s0[reg] = -1e30f;
      if (ro + 32 > qloc) s1[reg] = -1e30f;
    }
  }
  // max (defer-rescale T13), log2 domain
  float tm[16];
#pragma unroll
  for (int i = 0; i < 16; ++i) tm[i] = fmaxf(s0[i], s1[i]);
#pragma unroll
  for (int off = 8; off >= 1; off >>= 1)
#pragma unroll
    for (int i = 0; i < off; ++i) tm[i] = fmaxf(tm[i], tm[i + off]);
  float rmax = fmaxf(tm[0], __shfl_xor(tm[0], 32));
  bool need = __any(rmax > mrow + 11.5f);
  if (need) {
    float mnew = fmaxf(mrow, rmax);
    float osc = exp2f(mrow - mnew);
#pragma unroll
    for (int reg = 0; reg < 16; ++reg) {
      int rs = (reg & 3) + 8 * (reg >> 2) + 4 * h;
      float o = __shfl(osc, rs);
      acc0[reg] *= o;
      acc1[reg] *= o;
    }
    lrow *= osc;
    mrow = mnew;
  }
#pragma unroll
  for (int i = 0; i < 16; ++i) {
    s0[i] = exp2f(s0[i] - mrow);
    s1[i] = exp2f(s1[i] - mrow);
  }
  float ts[16];
#pragma unroll
  for (int i = 0; i < 16; ++i) ts[i] = s0[i] + s1[i];
#pragma unroll
  for (int off = 8; off >= 1; off >>= 1)
#pragma unroll
    for (int i = 0; i < off; ++i) ts[i] += ts[i + off];
  lrow += ts[0] + __shfl_xor(ts[0], 32);

  // in-register P -> A-fragment repack
  unsigned W0[4][2], W1[4][2], X0[4][2], X1[4][2];
#pragma unroll
  for (int sp = 0; sp < 4; ++sp)
#pragma unroll
    for (int u = 0; u < 2; ++u) {
      W0[sp][u] = packw(s0[sp * 4 + 2 * u], s0[sp * 4 + 2 * u + 1]);
      W1[sp][u] = packw(s1[sp * 4 + 2 * u], s1[sp * 4 + 2 * u + 1]);
    }
#pragma unroll
  for (int sp = 0; sp < 4; ++sp)
#pragma unroll
    for (int u = 0; u < 2; ++u) {
      X0[sp][u] = (unsigned)__shfl_xor((int)W0[sp][u], 32);
      X1[sp][u] = (unsigned)__shfl_xor((int)W1[sp][u], 32);
    }
  // PV (V from LDS)
  __builtin_amdgcn_s_setprio(1);
#pragma unroll
  for (int ks = 0; ks < 4; ++ks) {
    const unsigned (*W)[2] = (ks < 2) ? W0 : W1;
    const unsigned (*X)[2] = (ks < 2) ? X0 : X1;
    const int c = ks & 1;
    unsigned m0 = h ? X[2 * c + 1][0] : W[2 * c][0];
    unsigned m1 = h ? X[2 * c + 1][1] : W[2 * c][1];
    unsigned m2 = h ? W[2 * c + 1][0] : X[2 * c][0];
    unsigned m3 = h ? W[2 * c + 1][1] : X[2 * c][1];
    u32x4 pw = {m0, m1, m2, m3};
    bf16x8 pf = __builtin_bit_cast(bf16x8, pw);
    bf16x8 vf0 = frag64(Vt, l31, ks * 32 + h * 16);
    bf16x8 vf1 = frag64(Vt, 32 + l31, ks * 32 + h * 16);
    acc0 = __builtin_amdgcn_mfma_f32_32x32x16_bf16(pf, vf0, acc0, 0, 0, 0);
    acc1 = __builtin_amdgcn_mfma_f32_32x32x16_bf16(pf, vf1, acc1, 0, 0, 0);
  }
  __builtin_amdgcn_s_setprio(0);
}

__global__ __launch_bounds__(256) void attn_kernel(
    const bf16* __restrict__ q, const bf16* __restrict__ k,
    const bf16* __restrict__ vt, bf16* __restrict__ att)
{
  __shared__ bf16 Ks[4][64 * 64];
  __shared__ bf16 Vs[4][64 * 64];
  const int t = threadIdx.x;
  const int w = t >> 6;
  const int lane = t & 63;
  const int l31 = lane & 31;
  const int h = lane >> 5;

  // decode (j, bh) with complementary pairing: blocks idx and idx+256 sum to const work
  const int idx = blockIdx.x;
  const int half = idx >> 8;
  const int sub = idx & 255;
  const int bh = sub & 31;
  const int j = half ? (sub >> 5) : (15 - (sub >> 5));

  const int strip = 2 * j + (w >> 1);      // this wave's 64-row strip
  const int myN = strip + 1;               // kv tiles this wave computes
  const int npair = j + 1;                 // tile-pairs staged by the block
  const int q0w = j * 128 + w * 32;        // this wave's 32 q-rows
  const int qloc = (w & 1) * 32 + l31;     // row within strip

  const bf16* qb = q + (size_t)bh * SEQ * HD;
  const char* kbB = (const char*)(k + (size_t)bh * SEQ * HD);
  const char* vbB = (const char*)(vt + (size_t)bh * HD * SEQ);

  // Q fragments (B operand of 32x32x16)
  bf16x8 qf[4];
#pragma unroll
  for (int s = 0; s < 4; ++s)
    qf[s] = *reinterpret_cast<const bf16x8*>(qb + (size_t)(q0w + l31) * HD + s * 16 + h * 8);

  f32x16 acc0 = {}, acc1 = {};
  float mrow = -1e30f, lrow = 0.f;

  // prologue: stage pair 0 (tiles 0,1), then pair 1 (tiles 2,3) — 8 loads each
  stage_tile(kbB, 128, 0, (char*)Ks[0], t);
  stage_tile(vbB, 4096, 0, (char*)Vs[0], t);
  stage_tile(kbB + 8192, 128, 0, (char*)Ks[1], t);
  stage_tile(vbB, 4096, 128, (char*)Vs[1], t);
  if (npair > 1) {
    stage_tile(kbB + 2 * 8192, 128, 0, (char*)Ks[2], t);
    stage_tile(vbB, 4096, 2 * 128, (char*)Vs[2], t);
    stage_tile(kbB + 3 * 8192, 128, 0, (char*)Ks[3], t);
    stage_tile(vbB, 4096, 3 * 128, (char*)Vs[3], t);
  }

  for (int u = 0; u < npair; ++u) {
    if (u < npair - 1) {
      asm volatile("s_waitcnt vmcnt(8)" ::: "memory");   // pair u arrived; pair u+1 in flight
    } else {
      asm volatile("s_waitcnt vmcnt(0)" ::: "memory");
    }
    __builtin_amdgcn_sched_barrier(0);
    __builtin_amdgcn_s_barrier();          // pair u visible everywhere; pair-u slots rewritable afterwards? no: after SECOND barrier

    const int t0 = 2 * u, t1 = 2 * u + 1;
    const int s0i = t0 & 3, s1i = t1 & 3;
    tile_step((const char*)Ks[s0i], (const char*)Vs[s0i], qf, acc0, acc1,
              mrow, lrow, l31, h, t0 == strip, qloc);
    if (t1 < myN)
      tile_step((const char*)Ks[s1i], (const char*)Vs[s1i], qf, acc0, acc1,
                mrow, lrow, l31, h, t1 == strip, qloc);

    __builtin_amdgcn_s_barrier();          // all waves done reading pair u
    __builtin_amdgcn_sched_barrier(0);
    if (u + 2 < npair) {
      int tt = 2 * u + 4;                  // overwrite pair-u slots (safe: barrier above)
      stage_tile(kbB + (size_t)tt * 8192, 128, 0, (char*)Ks[tt & 3], t);
      stage_tile(vbB, 4096, tt * 128, (char*)Vs[tt & 3], t);
      stage_tile(kbB + (size_t)(tt + 1) * 8192, 128, 0, (char*)Ks[(tt + 1) & 3], t);
      stage_tile(vbB, 4096, (tt + 1) * 128, (char*)Vs[(tt + 1) & 3], t);
    }
  }

  // ---- normalize + write: O[q0w + row][d], row = (reg&3)+8*(reg>>2)+4h ----
#pragma unroll
  for (int reg = 0; reg < 16; ++reg) {
    int rs = (reg & 3) + 8 * (reg >> 2) + 4 * h;
    float li = __shfl(lrow, rs);
    size_t base = ((size_t)bh * SEQ + q0w + rs) * HD;
    att[base + l31]      = (bf16)(acc0[reg] / li);
    att[base + 32 + l31] = (bf16)(acc1[reg] / li);
  }
}

extern "C" void kernel_launch(void* const* d_in, const int* in_sizes, int n_in,
                              void* d_out, int out_size, void* d_ws, size_t ws_size,
                              hipStream_t stream) {
  const float* x  = (const float*)d_in[0];
  const int* pos  = (const int*)d_in[1];
  const float* Wq = (const float*)d_in[2];
  const float* Wk = (const float*)d_in[3];
  const float* Wv = (const float*)d_in[4];
  const float* Wo = (const float*)d_in[5];
  float* out = (float*)d_out;

  char* p = (char*)d_ws;
  bf16* xb   = (bf16*)p; p += (size_t)MTOT * DM * 2;
  bf16* wqb  = (bf16*)p; p += (size_t)DM * DM * 2;
  bf16* wkb  = (bf16*)p; p += (size_t)DM * DM * 2;
  bf16* wvb  = (bf16*)p; p += (size_t)DM * DM * 2;
  bf16* wob  = (bf16*)p; p += (size_t)DM * DM * 2;
  bf16* qb   = (bf16*)p; p += (size_t)MTOT * DM * 2;
  bf16* kb   = (bf16*)p; p += (size_t)MTOT * DM * 2;
  bf16* vtb  = (bf16*)p; p += (size_t)MTOT * DM * 2;
  bf16* attb = (bf16*)p; p += (size_t)MTOT * DM * 2;
  float2* tab = (float2*)p; p += (size_t)MTOT * 32 * sizeof(float2);

  cvt_kernel<<<(MTOT * DM / 4 + 255) / 256, 256, 0, stream>>>(x, xb, MTOT * DM / 4);
  cvt4_kernel<<<(4 * 262144 + 255) / 256, 256, 0, stream>>>(Wq, Wk, Wv, Wo, wqb);
  rope_tab_kernel<<<(MTOT * 32 + 255) / 256, 256, 0, stream>>>(pos, tab);

  gemm_qkv<<<dim3(24, MTOT / 128), 256, 0, stream>>>(xb, wqb, wkb, wvb, qb, kb, vtb, tab);

  attn_kernel<<<512, 256, 0, stream>>>(qb, kb, vtb, attb);

  gemm_out<<<dim3(DM / 128, MTOT / 128), 256, 0, stream>>>(attb, wob, out);
}

// Round 7
// 141.688 us; speedup vs baseline: 1.2760x; 1.1023x over previous
//
#include <hip/hip_runtime.h>
#include <hip/hip_bf16.h>

typedef __bf16 bf16;
typedef __bf16 bf16x4 __attribute__((ext_vector_type(4)));
typedef __bf16 bf16x8 __attribute__((ext_vector_type(8)));
typedef float f32x4 __attribute__((ext_vector_type(4)));
typedef float f32x16 __attribute__((ext_vector_type(16)));
typedef unsigned int u32x4 __attribute__((ext_vector_type(4)));

#define NH 16
#define HD 64
#define SEQ 2048
#define DM 1024
#define MTOT 4096   // B*S

__device__ __forceinline__ void gload_lds16(const void* g, void* l) {
  __builtin_amdgcn_global_load_lds(
      (const __attribute__((address_space(1))) void*)g,
      (__attribute__((address_space(3))) void*)l, 16, 0, 0);
}

// ---------------- fp32 -> bf16 conversion (vectorized) ----------------
__global__ void cvt_kernel(const float* __restrict__ in, bf16* __restrict__ out, int n4) {
  int i = blockIdx.x * blockDim.x + threadIdx.x;
  if (i >= n4) return;
  float4 v = reinterpret_cast<const float4*>(in)[i];
  bf16x4 o;
  o[0] = (bf16)v.x; o[1] = (bf16)v.y; o[2] = (bf16)v.z; o[3] = (bf16)v.w;
  *reinterpret_cast<bf16x4*>(out + (size_t)i * 4) = o;
}

// 4 weight matrices (1M elems each) -> contiguous bf16 out
__global__ void cvt4_kernel(const float* __restrict__ w0, const float* __restrict__ w1,
                            const float* __restrict__ w2, const float* __restrict__ w3,
                            bf16* __restrict__ out) {
  int i = blockIdx.x * blockDim.x + threadIdx.x;   // 0 .. 4*262144-1
  int seg = i >> 18;
  int j = i & 262143;
  const float* src = seg == 0 ? w0 : seg == 1 ? w1 : seg == 2 ? w2 : w3;
  float4 v = reinterpret_cast<const float4*>(src)[j];
  bf16x4 o;
  o[0] = (bf16)v.x; o[1] = (bf16)v.y; o[2] = (bf16)v.z; o[3] = (bf16)v.w;
  *reinterpret_cast<bf16x4*>(out + ((size_t)seg << 20) + (size_t)j * 4) = o;
}

// ---------------- RoPE cos/sin table: tab[m][i2] = (cos, sin) ----------------
__global__ void rope_tab_kernel(const int* __restrict__ pos, float2* __restrict__ tab) {
  int i = blockIdx.x * blockDim.x + threadIdx.x;
  if (i >= MTOT * 32) return;
  int m = i >> 5, i2 = i & 31;
  float pf = (float)pos[m];
  float inv = 1.0f / powf(10000.0f, (float)(2 * i2) * (1.0f / 64.0f));
  float a = pf * inv;
  tab[i] = make_float2(cosf(a), sinf(a));
}

// ---------------- fused QKV projection GEMM ----------------
// blockIdx.x in 0..23: proj = x>>3 (0=Q,1=K,2=V), n0 = (x&7)*128.
// Q: RoPE + 0.125*log2e scale (attn works in exp2 domain) -> [B,H,S,hd]
// K: RoPE -> [B,H,S,hd]; V: -> [B,H,hd,S]
__global__ __launch_bounds__(256) void gemm_qkv(
    const bf16* __restrict__ A, const bf16* __restrict__ wq,
    const bf16* __restrict__ wk, const bf16* __restrict__ wv,
    bf16* __restrict__ outq, bf16* __restrict__ outk, bf16* __restrict__ outv,
    const float2* __restrict__ tab)
{
  __shared__ bf16 As[128 * 32];
  __shared__ bf16 Bs[128 * 32];
  const int t = threadIdx.x;
  const int w = t >> 6;
  const int lane = t & 63;
  const int lr = lane & 15;
  const int lg = lane >> 4;
  const int lk = lg << 3;
  const int m0 = blockIdx.y * 128;
  const int proj = blockIdx.x >> 3;
  const int n0 = (blockIdx.x & 7) * 128;
  const bf16* Bw = proj == 0 ? wq : proj == 1 ? wk : wv;
  const int wr = w >> 1, wc = w & 1;

  f32x4 acc[4][4] = {};

  for (int k0 = 0; k0 < DM; k0 += 32) {
#pragma unroll
    for (int pp = 0; pp < 2; ++pp) {
      int chunk = pp * 256 + t;
      int r = chunk >> 2;
      int c = (chunk & 3) << 3;
      gload_lds16(A + (size_t)(m0 + r) * DM + k0 + c, (char*)As + (pp * 256 + w * 64) * 16);
      gload_lds16(Bw + (size_t)(n0 + r) * DM + k0 + c, (char*)Bs + (pp * 256 + w * 64) * 16);
    }
    __syncthreads();
    bf16x8 af[4], bfr[4];
#pragma unroll
    for (int f = 0; f < 4; ++f) {
      af[f]  = *reinterpret_cast<const bf16x8*>(As + (wr * 64 + f * 16 + lr) * 32 + lk);
      bfr[f] = *reinterpret_cast<const bf16x8*>(Bs + (wc * 64 + f * 16 + lr) * 32 + lk);
    }
#pragma unroll
    for (int i = 0; i < 4; ++i)
#pragma unroll
      for (int j = 0; j < 4; ++j)
        acc[i][j] = __builtin_amdgcn_mfma_f32_16x16x32_bf16(af[i], bfr[j], acc[i][j], 0, 0, 0);
    __syncthreads();
  }

  if (proj < 2) {
    bf16* outb = proj ? outk : outq;
#pragma unroll
    for (int j = 0; j < 4; ++j) {
      int n = n0 + wc * 64 + j * 16 + lr;
      int h = n >> 6, d = n & 63;
      int i2 = d >> 1;
      bool odd = d & 1;
#pragma unroll
      for (int i = 0; i < 4; ++i) {
#pragma unroll
        for (int rr = 0; rr < 4; ++rr) {
          int m = m0 + wr * 64 + i * 16 + lg * 4 + rr;
          float v = acc[i][j][rr];
          float o = __shfl_xor(v, 1);
          float2 cs = tab[(m << 5) + i2];
          float res = odd ? (v * cs.x + o * cs.y) : (v * cs.x - o * cs.y);
          if (proj == 0) res *= 0.125f * 1.44269504f;   // 1/sqrt(hd) * log2(e)
          outb[((size_t)((m >> 11) * NH + h) * SEQ + (m & 2047)) * HD + d] = (bf16)res;
        }
      }
    }
  } else {
#pragma unroll
    for (int j = 0; j < 4; ++j) {
      int n = n0 + wc * 64 + j * 16 + lr;
      int h = n >> 6, d = n & 63;
#pragma unroll
      for (int i = 0; i < 4; ++i) {
#pragma unroll
        for (int rr = 0; rr < 4; ++rr) {
          int m = m0 + wr * 64 + i * 16 + lg * 4 + rr;
          outv[((size_t)((m >> 11) * NH + h) * HD + d) * SEQ + (m & 2047)] = (bf16)acc[i][j][rr];
        }
      }
    }
  }
}

// ---------------- output projection GEMM (A from att [B,H,S,hd]) ----------------
__global__ __launch_bounds__(256) void gemm_out(
    const bf16* __restrict__ A, const bf16* __restrict__ Bw, float* __restrict__ outf)
{
  __shared__ bf16 As[128 * 32];
  __shared__ bf16 Bs[128 * 32];
  const int t = threadIdx.x;
  const int w = t >> 6;
  const int lane = t & 63;
  const int lr = lane & 15;
  const int lg = lane >> 4;
  const int lk = lg << 3;
  const int m0 = blockIdx.y * 128;
  const int n0 = blockIdx.x * 128;
  const int wr = w >> 1, wc = w & 1;

  f32x4 acc[4][4] = {};

  for (int k0 = 0; k0 < DM; k0 += 32) {
#pragma unroll
    for (int pp = 0; pp < 2; ++pp) {
      int chunk = pp * 256 + t;
      int r = chunk >> 2;
      int c = (chunk & 3) << 3;
      int m = m0 + r;
      int kk = k0 + c;
      const bf16* ga = A + (((size_t)((m >> 11) * NH + (kk >> 6)) * SEQ + (m & 2047)) * HD + (kk & 63));
      gload_lds16(ga, (char*)As + (pp * 256 + w * 64) * 16);
      gload_lds16(Bw + (size_t)(n0 + r) * DM + k0 + c, (char*)Bs + (pp * 256 + w * 64) * 16);
    }
    __syncthreads();
    bf16x8 af[4], bfr[4];
#pragma unroll
    for (int f = 0; f < 4; ++f) {
      af[f]  = *reinterpret_cast<const bf16x8*>(As + (wr * 64 + f * 16 + lr) * 32 + lk);
      bfr[f] = *reinterpret_cast<const bf16x8*>(Bs + (wc * 64 + f * 16 + lr) * 32 + lk);
    }
#pragma unroll
    for (int i = 0; i < 4; ++i)
#pragma unroll
      for (int j = 0; j < 4; ++j)
        acc[i][j] = __builtin_amdgcn_mfma_f32_16x16x32_bf16(af[i], bfr[j], acc[i][j], 0, 0, 0);
    __syncthreads();
  }

#pragma unroll
  for (int j = 0; j < 4; ++j) {
    int n = n0 + wc * 64 + j * 16 + lr;
#pragma unroll
    for (int i = 0; i < 4; ++i) {
#pragma unroll
      for (int rr = 0; rr < 4; ++rr) {
        int m = m0 + wr * 64 + i * 16 + lg * 4 + rr;
        outf[(size_t)m * DM + n] = acc[i][j][rr];
      }
    }
  }
}

// ---------------- flash attention ----------------
// 512 blocks x 512 threads (8 waves). Waves 0-3 = kv-parity 0, waves 4-7 =
// kv-parity 1 of the SAME q-rows (strips 2j, 2j+1). Per pair-iteration each
// wave computes ONE tile (2u+par) — the two parity groups run concurrently on
// the two tiles of the staged pair. Epilogue: flash-merge partials via LDS.
// K/V staged coalesced+swizzled, pair ring of 2, counted vmcnt across barriers.
__device__ __forceinline__ void stage512(const char* gRow0, size_t rowStrideB, int colByte0,
                                         char* lds, int t) {
  int o = t * 16;                  // 512 threads x 16 B = one 64x64 bf16 tile
  int r = o >> 7;
  int cb = o & 127;
  int cbs = cb ^ ((r & 7) << 4);
  gload_lds16(gRow0 + (size_t)r * rowStrideB + colByte0 + cbs, lds + o);
}

__device__ __forceinline__ bf16x8 frag64(const char* tile, int row, int colByte) {
  int b = row * 128 + (colByte ^ ((row & 7) << 4));
  return *reinterpret_cast<const bf16x8*>(tile + b);
}

__device__ __forceinline__ unsigned packw(float a, float b) {
  unsigned short la = __builtin_bit_cast(unsigned short, (bf16)a);
  unsigned short lb = __builtin_bit_cast(unsigned short, (bf16)b);
  return (unsigned)la | ((unsigned)lb << 16);
}

// one kv-tile: QK^T (swapped operands), online softmax, in-register repack, PV
__device__ __forceinline__ void tile_step(const char* Kt, const char* Vt,
                                          const bf16x8* qf,
                                          f32x16& acc0, f32x16& acc1,
                                          float& mrow, float& lrow,
                                          int l31, int h, bool domask, int qloc) {
  f32x16 s0 = {}, s1 = {};
  __builtin_amdgcn_s_setprio(1);
#pragma unroll
  for (int s = 0; s < 4; ++s) {
    bf16x8 kf0 = frag64(Kt, l31, s * 32 + h * 16);
    bf16x8 kf1 = frag64(Kt, 32 + l31, s * 32 + h * 16);
    s0 = __builtin_amdgcn_mfma_f32_32x32x16_bf16(kf0, qf[s], s0, 0, 0, 0);
    s1 = __builtin_amdgcn_mfma_f32_32x32x16_bf16(kf1, qf[s], s1, 0, 0, 0);
  }
  __builtin_amdgcn_s_setprio(0);
  if (domask) {
#pragma unroll
    for (int reg = 0; reg < 16; ++reg) {
      int ro = (reg & 3) + 8 * (reg >> 2) + 4 * h;
      if (ro > qloc) s0[reg] = -1e30f;
      if (ro + 32 > qloc) s1[reg] = -1e30f;
    }
  }
  // max (defer-rescale T13), log2 domain
  float tm[16];
#pragma unroll
  for (int i = 0; i < 16; ++i) tm[i] = fmaxf(s0[i], s1[i]);
#pragma unroll
  for (int off = 8; off >= 1; off >>= 1)
#pragma unroll
    for (int i = 0; i < off; ++i) tm[i] = fmaxf(tm[i], tm[i + off]);
  float rmax = fmaxf(tm[0], __shfl_xor(tm[0], 32));
  bool need = __any(rmax > mrow + 11.5f);
  if (need) {
    float mnew = fmaxf(mrow, rmax);
    float osc = exp2f(mrow - mnew);
#pragma unroll
    for (int reg = 0; reg < 16; ++reg) {
      int rs = (reg & 3) + 8 * (reg >> 2) + 4 * h;
      float o = __shfl(osc, rs);
      acc0[reg] *= o;
      acc1[reg] *= o;
    }
    lrow *= osc;
    mrow = mnew;
  }
#pragma unroll
  for (int i = 0; i < 16; ++i) {
    s0[i] = exp2f(s0[i] - mrow);
    s1[i] = exp2f(s1[i] - mrow);
  }
  float ts[16];
#pragma unroll
  for (int i = 0; i < 16; ++i) ts[i] = s0[i] + s1[i];
#pragma unroll
  for (int off = 8; off >= 1; off >>= 1)
#pragma unroll
    for (int i = 0; i < off; ++i) ts[i] += ts[i + off];
  lrow += ts[0] + __shfl_xor(ts[0], 32);

  // in-register P -> A-fragment repack
  unsigned W0[4][2], W1[4][2], X0[4][2], X1[4][2];
#pragma unroll
  for (int sp = 0; sp < 4; ++sp)
#pragma unroll
    for (int u = 0; u < 2; ++u) {
      W0[sp][u] = packw(s0[sp * 4 + 2 * u], s0[sp * 4 + 2 * u + 1]);
      W1[sp][u] = packw(s1[sp * 4 + 2 * u], s1[sp * 4 + 2 * u + 1]);
    }
#pragma unroll
  for (int sp = 0; sp < 4; ++sp)
#pragma unroll
    for (int u = 0; u < 2; ++u) {
      X0[sp][u] = (unsigned)__shfl_xor((int)W0[sp][u], 32);
      X1[sp][u] = (unsigned)__shfl_xor((int)W1[sp][u], 32);
    }
  // PV (V from LDS)
  __builtin_amdgcn_s_setprio(1);
#pragma unroll
  for (int ks = 0; ks < 4; ++ks) {
    const unsigned (*W)[2] = (ks < 2) ? W0 : W1;
    const unsigned (*X)[2] = (ks < 2) ? X0 : X1;
    const int c = ks & 1;
    unsigned m0 = h ? X[2 * c + 1][0] : W[2 * c][0];
    unsigned m1 = h ? X[2 * c + 1][1] : W[2 * c][1];
    unsigned m2 = h ? W[2 * c + 1][0] : X[2 * c][0];
    unsigned m3 = h ? W[2 * c + 1][1] : X[2 * c][1];
    u32x4 pw = {m0, m1, m2, m3};
    bf16x8 pf = __builtin_bit_cast(bf16x8, pw);
    bf16x8 vf0 = frag64(Vt, l31, ks * 32 + h * 16);
    bf16x8 vf1 = frag64(Vt, 32 + l31, ks * 32 + h * 16);
    acc0 = __builtin_amdgcn_mfma_f32_32x32x16_bf16(pf, vf0, acc0, 0, 0, 0);
    acc1 = __builtin_amdgcn_mfma_f32_32x32x16_bf16(pf, vf1, acc1, 0, 0, 0);
  }
  __builtin_amdgcn_s_setprio(0);
}

__global__ __launch_bounds__(512, 4) void attn_kernel(
    const bf16* __restrict__ q, const bf16* __restrict__ k,
    const bf16* __restrict__ vt, bf16* __restrict__ att)
{
  __shared__ __align__(16) char pool[65536];   // Ks[4] @ 0, Vs[4] @ 32768; merge buf at end
  const int t = threadIdx.x;
  const int w = t >> 6;
  const int wsub = w & 3;
  const int par = w >> 2;          // kv-tile parity this wave handles
  const int lane = t & 63;
  const int l31 = lane & 31;
  const int h = lane >> 5;

  // decode (j, bh) with complementary pairing: blocks idx and idx+256 sum to const work
  const int idx = blockIdx.x;
  const int half = idx >> 8;
  const int sub = idx & 255;
  const int bh = sub & 31;
  const int j = half ? (sub >> 5) : (15 - (sub >> 5));

  const int strip = 2 * j + (wsub >> 1);   // this wave's 64-row strip
  const int myN = strip + 1;               // kv tiles for this strip
  const int npair = j + 1;                 // tile-pairs staged by the block
  const int q0w = j * 128 + wsub * 32;     // this wave's 32 q-rows
  const int qloc = (wsub & 1) * 32 + l31;  // row within strip

  const bf16* qb = q + (size_t)bh * SEQ * HD;
  const char* kbB = (const char*)(k + (size_t)bh * SEQ * HD);
  const char* vbB = (const char*)(vt + (size_t)bh * HD * SEQ);

  // Q fragments (B operand of 32x32x16)
  bf16x8 qf[4];
#pragma unroll
  for (int s = 0; s < 4; ++s)
    qf[s] = *reinterpret_cast<const bf16x8*>(qb + (size_t)(q0w + l31) * HD + s * 16 + h * 8);

  f32x16 acc0 = {}, acc1 = {};
  float mrow = -1e30f, lrow = 0.f;

  // prologue: stage pair 0 (tiles 0,1); pair 1 (tiles 2,3) — 4 loads per pair per thread
  stage512(kbB, 128, 0, pool + 0 * 8192, t);
  stage512(vbB, 4096, 0, pool + 32768 + 0 * 8192, t);
  stage512(kbB + 8192, 128, 0, pool + 1 * 8192, t);
  stage512(vbB, 4096, 128, pool + 32768 + 1 * 8192, t);
  if (npair > 1) {
    stage512(kbB + 2 * 8192, 128, 0, pool + 2 * 8192, t);
    stage512(vbB, 4096, 2 * 128, pool + 32768 + 2 * 8192, t);
    stage512(kbB + 3 * 8192, 128, 0, pool + 3 * 8192, t);
    stage512(vbB, 4096, 3 * 128, pool + 32768 + 3 * 8192, t);
  }

  for (int u = 0; u < npair; ++u) {
    if (u < npair - 1) {
      asm volatile("s_waitcnt vmcnt(4)" ::: "memory");   // pair u arrived; pair u+1 in flight
    } else {
      asm volatile("s_waitcnt vmcnt(0)" ::: "memory");
    }
    __builtin_amdgcn_sched_barrier(0);
    __builtin_amdgcn_s_barrier();          // pair u visible to all waves

    const int tt = 2 * u + par;            // this wave's tile in the pair
    if (tt < myN)
      tile_step(pool + (tt & 3) * 8192, pool + 32768 + (tt & 3) * 8192, qf,
                acc0, acc1, mrow, lrow, l31, h, tt == strip, qloc);

    __builtin_amdgcn_s_barrier();          // all waves done reading pair u
    __builtin_amdgcn_sched_barrier(0);
    if (u + 2 < npair) {
      int nt = 2 * u + 4;                  // overwrite pair-u slots (safe: barrier above)
      stage512(kbB + (size_t)nt * 8192, 128, 0, pool + (nt & 3) * 8192, t);
      stage512(vbB, 4096, nt * 128, pool + 32768 + (nt & 3) * 8192, t);
      stage512(kbB + (size_t)(nt + 1) * 8192, 128, 0, pool + ((nt + 1) & 3) * 8192, t);
      stage512(vbB, 4096, (nt + 1) * 128, pool + 32768 + ((nt + 1) & 3) * 8192, t);
    }
  }

  // ---- flash-merge the two parity partials via LDS, then write out ----
  // parity-1 wave wsub writes 34x64 f32 region; parity-0 wave wsub merges.
  float* mb = (float*)pool;
  float* reg = mb + wsub * (34 * 64);
  if (par == 1) {
#pragma unroll
    for (int i = 0; i < 16; ++i) reg[i * 64 + lane] = acc0[i];
#pragma unroll
    for (int i = 0; i < 16; ++i) reg[(16 + i) * 64 + lane] = acc1[i];
    reg[32 * 64 + lane] = mrow;
    reg[33 * 64 + lane] = lrow;
  }
  __syncthreads();
  if (par == 0) {
    float mB = reg[32 * 64 + lane];
    float lB = reg[33 * 64 + lane];
    float mM = fmaxf(mrow, mB);
    float alpha = exp2f(mrow - mM);
    float beta  = exp2f(mB - mM);
    float linv = 1.0f / (alpha * lrow + beta * lB);
#pragma unroll
    for (int rg = 0; rg < 16; ++rg) {
      int rs = (rg & 3) + 8 * (rg >> 2) + 4 * h;
      float a  = __shfl(alpha, rs);
      float b  = __shfl(beta, rs);
      float li = __shfl(linv, rs);
      float o0 = (a * acc0[rg] + b * reg[rg * 64 + lane]) * li;
      float o1 = (a * acc1[rg] + b * reg[(16 + rg) * 64 + lane]) * li;
      size_t base = ((size_t)bh * SEQ + q0w + rs) * HD;
      att[base + l31]      = (bf16)o0;
      att[base + 32 + l31] = (bf16)o1;
    }
  }
}

extern "C" void kernel_launch(void* const* d_in, const int* in_sizes, int n_in,
                              void* d_out, int out_size, void* d_ws, size_t ws_size,
                              hipStream_t stream) {
  const float* x  = (const float*)d_in[0];
  const int* pos  = (const int*)d_in[1];
  const float* Wq = (const float*)d_in[2];
  const float* Wk = (const float*)d_in[3];
  const float* Wv = (const float*)d_in[4];
  const float* Wo = (const float*)d_in[5];
  float* out = (float*)d_out;

  char* p = (char*)d_ws;
  bf16* xb   = (bf16*)p; p += (size_t)MTOT * DM * 2;
  bf16* wqb  = (bf16*)p; p += (size_t)DM * DM * 2;
  bf16* wkb  = (bf16*)p; p += (size_t)DM * DM * 2;
  bf16* wvb  = (bf16*)p; p += (size_t)DM * DM * 2;
  bf16* wob  = (bf16*)p; p += (size_t)DM * DM * 2;
  bf16* qb   = (bf16*)p; p += (size_t)MTOT * DM * 2;
  bf16* kb   = (bf16*)p; p += (size_t)MTOT * DM * 2;
  bf16* vtb  = (bf16*)p; p += (size_t)MTOT * DM * 2;
  bf16* attb = (bf16*)p; p += (size_t)MTOT * DM * 2;
  float2* tab = (float2*)p; p += (size_t)MTOT * 32 * sizeof(float2);

  cvt_kernel<<<(MTOT * DM / 4 + 255) / 256, 256, 0, stream>>>(x, xb, MTOT * DM / 4);
  cvt4_kernel<<<(4 * 262144 + 255) / 256, 256, 0, stream>>>(Wq, Wk, Wv, Wo, wqb);
  rope_tab_kernel<<<(MTOT * 32 + 255) / 256, 256, 0, stream>>>(pos, tab);

  gemm_qkv<<<dim3(24, MTOT / 128), 256, 0, stream>>>(xb, wqb, wkb, wvb, qb, kb, vtb, tab);

  attn_kernel<<<512, 512, 0, stream>>>(qb, kb, vtb, attb);

  gemm_out<<<dim3(DM / 128, MTOT / 128), 256, 0, stream>>>(attb, wob, out);
}

// Round 8
// 140.521 us; speedup vs baseline: 1.2866x; 1.0083x over previous
//
#include <hip/hip_runtime.h>
#include <hip/hip_bf16.h>

typedef __bf16 bf16;
typedef __bf16 bf16x4 __attribute__((ext_vector_type(4)));
typedef __bf16 bf16x8 __attribute__((ext_vector_type(8)));
typedef float f32x4 __attribute__((ext_vector_type(4)));
typedef float f32x16 __attribute__((ext_vector_type(16)));
typedef unsigned int u32x4 __attribute__((ext_vector_type(4)));

#define NH 16
#define HD 64
#define SEQ 2048
#define DM 1024
#define MTOT 4096   // B*S

__device__ __forceinline__ void gload_lds16(const void* g, void* l) {
  __builtin_amdgcn_global_load_lds(
      (const __attribute__((address_space(1))) void*)g,
      (__attribute__((address_space(3))) void*)l, 16, 0, 0);
}

// ---------------- fp32 -> bf16 conversion (vectorized) ----------------
__global__ void cvt_kernel(const float* __restrict__ in, bf16* __restrict__ out, int n4) {
  int i = blockIdx.x * blockDim.x + threadIdx.x;
  if (i >= n4) return;
  float4 v = reinterpret_cast<const float4*>(in)[i];
  bf16x4 o;
  o[0] = (bf16)v.x; o[1] = (bf16)v.y; o[2] = (bf16)v.z; o[3] = (bf16)v.w;
  *reinterpret_cast<bf16x4*>(out + (size_t)i * 4) = o;
}

// 4 weight matrices (1M elems each) -> contiguous bf16 out
__global__ void cvt4_kernel(const float* __restrict__ w0, const float* __restrict__ w1,
                            const float* __restrict__ w2, const float* __restrict__ w3,
                            bf16* __restrict__ out) {
  int i = blockIdx.x * blockDim.x + threadIdx.x;   // 0 .. 4*262144-1
  int seg = i >> 18;
  int j = i & 262143;
  const float* src = seg == 0 ? w0 : seg == 1 ? w1 : seg == 2 ? w2 : w3;
  float4 v = reinterpret_cast<const float4*>(src)[j];
  bf16x4 o;
  o[0] = (bf16)v.x; o[1] = (bf16)v.y; o[2] = (bf16)v.z; o[3] = (bf16)v.w;
  *reinterpret_cast<bf16x4*>(out + ((size_t)seg << 20) + (size_t)j * 4) = o;
}

// ---------------- RoPE cos/sin table: tab[m][i2] = (cos, sin) ----------------
__global__ void rope_tab_kernel(const int* __restrict__ pos, float2* __restrict__ tab) {
  int i = blockIdx.x * blockDim.x + threadIdx.x;
  if (i >= MTOT * 32) return;
  int m = i >> 5, i2 = i & 31;
  float pf = (float)pos[m];
  float inv = 1.0f / powf(10000.0f, (float)(2 * i2) * (1.0f / 64.0f));
  float a = pf * inv;
  tab[i] = make_float2(cosf(a), sinf(a));
}

// ---------------- fused QKV projection GEMM, 256x256 tile, BK=32 ----------------
// grid (12, 16): blockIdx.x -> proj = x>>2 (0=Q,1=K,2=V), n0 = (x&3)*256 within proj.
// 512 threads = 8 waves (2M x 4N); per-wave C = 128x64 (acc[8][4]).
// LDS: double-buffered A[2][256*32] + B[2][256*32] bf16 = 64 KB. Counted-vmcnt ring:
// stage tile kt+1 before compute of kt; vmcnt(4) certifies kt with kt+1 in flight;
// raw s_barrier (no drain). 64B rows => fragment reads bank-uniform, no swizzle.
// Q: RoPE + 0.125*log2e -> [B,H,S,hd]; K: RoPE -> [B,H,S,hd]; V: -> [B,H,hd,S]
__global__ __launch_bounds__(512) void gemm_qkv(
    const bf16* __restrict__ A, const bf16* __restrict__ wAll,
    bf16* __restrict__ outq, bf16* __restrict__ outk, bf16* __restrict__ outv,
    const float2* __restrict__ tab)
{
  __shared__ bf16 As[2][256 * 32];
  __shared__ bf16 Bs[2][256 * 32];
  const int t = threadIdx.x;
  const int w = t >> 6;
  const int wm = w >> 2, wn = w & 3;
  const int lane = t & 63;
  const int lr = lane & 15;
  const int lg = lane >> 4;
  const int m0 = blockIdx.y * 256;
  const int proj = blockIdx.x >> 2;
  const int n0l = (blockIdx.x & 3) * 256;
  const char* Ab = (const char*)A;
  const char* Bb = (const char*)(wAll + ((size_t)proj << 20) + (size_t)n0l * DM);

  f32x4 acc[8][4] = {};

#define STAGE_QKV(KT, SLOT)                                                       \
  {                                                                               \
    _Pragma("unroll")                                                             \
    for (int p = 0; p < 2; ++p) {                                                 \
      int o = (p * 512 + t) * 16;                                                 \
      int r = o >> 6, cb = o & 63;                                                \
      gload_lds16(Ab + (size_t)(m0 + r) * 2048 + (KT) * 64 + cb,                  \
                  (char*)As[SLOT] + o);                                           \
    }                                                                             \
    _Pragma("unroll")                                                             \
    for (int p = 0; p < 2; ++p) {                                                 \
      int o = (p * 512 + t) * 16;                                                 \
      int r = o >> 6, cb = o & 63;                                                \
      gload_lds16(Bb + (size_t)r * 2048 + (KT) * 64 + cb, (char*)Bs[SLOT] + o);   \
    }                                                                             \
  }

  STAGE_QKV(0, 0);
  for (int kt = 0; kt < 32; ++kt) {
    if (kt + 1 < 32) {
      STAGE_QKV(kt + 1, (kt + 1) & 1);
      asm volatile("s_waitcnt vmcnt(4)" ::: "memory");   // tile kt landed; kt+1 in flight
    } else {
      asm volatile("s_waitcnt vmcnt(0)" ::: "memory");
    }
    __builtin_amdgcn_sched_barrier(0);
    __builtin_amdgcn_s_barrier();          // everyone's share of tile kt landed

    const bf16* Abuf = As[kt & 1];
    const bf16* Bbuf = Bs[kt & 1];
    bf16x8 af[8], bfr[4];
#pragma unroll
    for (int i = 0; i < 8; ++i)
      af[i] = *reinterpret_cast<const bf16x8*>(Abuf + (wm * 128 + i * 16 + lr) * 32 + lg * 8);
#pragma unroll
    for (int j = 0; j < 4; ++j)
      bfr[j] = *reinterpret_cast<const bf16x8*>(Bbuf + (wn * 64 + j * 16 + lr) * 32 + lg * 8);
    __builtin_amdgcn_s_setprio(1);
#pragma unroll
    for (int i = 0; i < 8; ++i)
#pragma unroll
      for (int j = 0; j < 4; ++j)
        acc[i][j] = __builtin_amdgcn_mfma_f32_16x16x32_bf16(af[i], bfr[j], acc[i][j], 0, 0, 0);
    __builtin_amdgcn_s_setprio(0);
    __builtin_amdgcn_s_barrier();          // all waves done reading tile kt (slot reusable)
  }

  if (proj < 2) {
    bf16* outb = proj ? outk : outq;
#pragma unroll
    for (int j = 0; j < 4; ++j) {
      int nl = n0l + wn * 64 + j * 16 + lr;
      int h = nl >> 6, d = nl & 63;
      int i2 = d >> 1;
      bool odd = d & 1;
#pragma unroll
      for (int i = 0; i < 8; ++i) {
#pragma unroll
        for (int rr = 0; rr < 4; ++rr) {
          int m = m0 + wm * 128 + i * 16 + lg * 4 + rr;
          float v = acc[i][j][rr];
          float o = __shfl_xor(v, 1);
          float2 cs = tab[(m << 5) + i2];
          float res = odd ? (v * cs.x + o * cs.y) : (v * cs.x - o * cs.y);
          if (proj == 0) res *= 0.125f * 1.44269504f;   // 1/sqrt(hd) * log2(e)
          outb[((size_t)((m >> 11) * NH + h) * SEQ + (m & 2047)) * HD + d] = (bf16)res;
        }
      }
    }
  } else {
#pragma unroll
    for (int j = 0; j < 4; ++j) {
      int nl = n0l + wn * 64 + j * 16 + lr;
      int h = nl >> 6, d = nl & 63;
#pragma unroll
      for (int i = 0; i < 8; ++i) {
#pragma unroll
        for (int rr = 0; rr < 4; ++rr) {
          int m = m0 + wm * 128 + i * 16 + lg * 4 + rr;
          outv[((size_t)((m >> 11) * NH + h) * HD + d) * SEQ + (m & 2047)] = (bf16)acc[i][j][rr];
        }
      }
    }
  }
#undef STAGE_QKV
}

// ---------------- output projection GEMM (A from att [B,H,S,hd]) ----------------
// 128x128 tile, BK=32, 4 waves, counted-vmcnt ring (same discipline as gemm_qkv).
__global__ __launch_bounds__(256) void gemm_out(
    const bf16* __restrict__ A, const bf16* __restrict__ Bw, float* __restrict__ outf)
{
  __shared__ bf16 As[2][128 * 32];
  __shared__ bf16 Bs[2][128 * 32];
  const int t = threadIdx.x;
  const int w = t >> 6;
  const int lane = t & 63;
  const int lr = lane & 15;
  const int lg = lane >> 4;
  const int m0 = blockIdx.y * 128;
  const int n0 = blockIdx.x * 128;
  const int wr = w >> 1, wc = w & 1;
  const char* Bb = (const char*)Bw;

  f32x4 acc[4][4] = {};

#define STAGE_OUT(KT, SLOT)                                                            \
  {                                                                                    \
    _Pragma("unroll")                                                                  \
    for (int p = 0; p < 2; ++p) {                                                      \
      int o = (p * 256 + t) * 16;                                                      \
      int r = o >> 6, cb = o & 63;                                                     \
      int m = m0 + r;                                                                  \
      const char* ga = (const char*)A +                                                \
          ((((size_t)(m >> 11) * NH + ((KT) >> 1)) * SEQ + (m & 2047)) * HD +          \
           ((KT) & 1) * 32) * 2 + cb;                                                  \
      gload_lds16(ga, (char*)As[SLOT] + o);                                            \
    }                                                                                  \
    _Pragma("unroll")                                                                  \
    for (int p = 0; p < 2; ++p) {                                                      \
      int o = (p * 256 + t) * 16;                                                      \
      int r = o >> 6, cb = o & 63;                                                     \
      gload_lds16(Bb + (size_t)(n0 + r) * 2048 + (KT) * 64 + cb, (char*)Bs[SLOT] + o); \
    }                                                                                  \
  }

  STAGE_OUT(0, 0);
  for (int kt = 0; kt < 32; ++kt) {
    if (kt + 1 < 32) {
      STAGE_OUT(kt + 1, (kt + 1) & 1);
      asm volatile("s_waitcnt vmcnt(4)" ::: "memory");
    } else {
      asm volatile("s_waitcnt vmcnt(0)" ::: "memory");
    }
    __builtin_amdgcn_sched_barrier(0);
    __builtin_amdgcn_s_barrier();

    const bf16* Abuf = As[kt & 1];
    const bf16* Bbuf = Bs[kt & 1];
    bf16x8 af[4], bfr[4];
#pragma unroll
    for (int f = 0; f < 4; ++f) {
      af[f]  = *reinterpret_cast<const bf16x8*>(Abuf + (wr * 64 + f * 16 + lr) * 32 + lg * 8);
      bfr[f] = *reinterpret_cast<const bf16x8*>(Bbuf + (wc * 64 + f * 16 + lr) * 32 + lg * 8);
    }
    __builtin_amdgcn_s_setprio(1);
#pragma unroll
    for (int i = 0; i < 4; ++i)
#pragma unroll
      for (int j = 0; j < 4; ++j)
        acc[i][j] = __builtin_amdgcn_mfma_f32_16x16x32_bf16(af[i], bfr[j], acc[i][j], 0, 0, 0);
    __builtin_amdgcn_s_setprio(0);
    __builtin_amdgcn_s_barrier();
  }

#pragma unroll
  for (int j = 0; j < 4; ++j) {
    int n = n0 + wc * 64 + j * 16 + lr;
#pragma unroll
    for (int i = 0; i < 4; ++i) {
#pragma unroll
      for (int rr = 0; rr < 4; ++rr) {
        int m = m0 + wr * 64 + i * 16 + lg * 4 + rr;
        outf[(size_t)m * DM + n] = acc[i][j][rr];
      }
    }
  }
#undef STAGE_OUT
}

// ---------------- flash attention (unchanged from r7) ----------------
__device__ __forceinline__ void stage512(const char* gRow0, size_t rowStrideB, int colByte0,
                                         char* lds, int t) {
  int o = t * 16;
  int r = o >> 7;
  int cb = o & 127;
  int cbs = cb ^ ((r & 7) << 4);
  gload_lds16(gRow0 + (size_t)r * rowStrideB + colByte0 + cbs, lds + o);
}

__device__ __forceinline__ bf16x8 frag64(const char* tile, int row, int colByte) {
  int b = row * 128 + (colByte ^ ((row & 7) << 4));
  return *reinterpret_cast<const bf16x8*>(tile + b);
}

__device__ __forceinline__ unsigned packw(float a, float b) {
  unsigned short la = __builtin_bit_cast(unsigned short, (bf16)a);
  unsigned short lb = __builtin_bit_cast(unsigned short, (bf16)b);
  return (unsigned)la | ((unsigned)lb << 16);
}

__device__ __forceinline__ void tile_step(const char* Kt, const char* Vt,
                                          const bf16x8* qf,
                                          f32x16& acc0, f32x16& acc1,
                                          float& mrow, float& lrow,
                                          int l31, int h, bool domask, int qloc) {
  f32x16 s0 = {}, s1 = {};
  __builtin_amdgcn_s_setprio(1);
#pragma unroll
  for (int s = 0; s < 4; ++s) {
    bf16x8 kf0 = frag64(Kt, l31, s * 32 + h * 16);
    bf16x8 kf1 = frag64(Kt, 32 + l31, s * 32 + h * 16);
    s0 = __builtin_amdgcn_mfma_f32_32x32x16_bf16(kf0, qf[s], s0, 0, 0, 0);
    s1 = __builtin_amdgcn_mfma_f32_32x32x16_bf16(kf1, qf[s], s1, 0, 0, 0);
  }
  __builtin_amdgcn_s_setprio(0);
  if (domask) {
#pragma unroll
    for (int reg = 0; reg < 16; ++reg) {
      int ro = (reg & 3) + 8 * (reg >> 2) + 4 * h;
      if (ro > qloc) s0[reg] = -1e30f;
      if (ro + 32 > qloc) s1[reg] = -1e30f;
    }
  }
  float tm[16];
#pragma unroll
  for (int i = 0; i < 16; ++i) tm[i] = fmaxf(s0[i], s1[i]);
#pragma unroll
  for (int off = 8; off >= 1; off >>= 1)
#pragma unroll
    for (int i = 0; i < off; ++i) tm[i] = fmaxf(tm[i], tm[i + off]);
  float rmax = fmaxf(tm[0], __shfl_xor(tm[0], 32));
  bool need = __any(rmax > mrow + 11.5f);
  if (need) {
    float mnew = fmaxf(mrow, rmax);
    float osc = exp2f(mrow - mnew);
#pragma unroll
    for (int reg = 0; reg < 16; ++reg) {
      int rs = (reg & 3) + 8 * (reg >> 2) + 4 * h;
      float o = __shfl(osc, rs);
      acc0[reg] *= o;
      acc1[reg] *= o;
    }
    lrow *= osc;
    mrow = mnew;
  }
#pragma unroll
  for (int i = 0; i < 16; ++i) {
    s0[i] = exp2f(s0[i] - mrow);
    s1[i] = exp2f(s1[i] - mrow);
  }
  float ts[16];
#pragma unroll
  for (int i = 0; i < 16; ++i) ts[i] = s0[i] + s1[i];
#pragma unroll
  for (int off = 8; off >= 1; off >>= 1)
#pragma unroll
    for (int i = 0; i < off; ++i) ts[i] += ts[i + off];
  lrow += ts[0] + __shfl_xor(ts[0], 32);

  unsigned W0[4][2], W1[4][2], X0[4][2], X1[4][2];
#pragma unroll
  for (int sp = 0; sp < 4; ++sp)
#pragma unroll
    for (int u = 0; u < 2; ++u) {
      W0[sp][u] = packw(s0[sp * 4 + 2 * u], s0[sp * 4 + 2 * u + 1]);
      W1[sp][u] = packw(s1[sp * 4 + 2 * u], s1[sp * 4 + 2 * u + 1]);
    }
#pragma unroll
  for (int sp = 0; sp < 4; ++sp)
#pragma unroll
    for (int u = 0; u < 2; ++u) {
      X0[sp][u] = (unsigned)__shfl_xor((int)W0[sp][u], 32);
      X1[sp][u] = (unsigned)__shfl_xor((int)W1[sp][u], 32);
    }
  __builtin_amdgcn_s_setprio(1);
#pragma unroll
  for (int ks = 0; ks < 4; ++ks) {
    const unsigned (*W)[2] = (ks < 2) ? W0 : W1;
    const unsigned (*X)[2] = (ks < 2) ? X0 : X1;
    const int c = ks & 1;
    unsigned m0 = h ? X[2 * c + 1][0] : W[2 * c][0];
    unsigned m1 = h ? X[2 * c + 1][1] : W[2 * c][1];
    unsigned m2 = h ? W[2 * c + 1][0] : X[2 * c][0];
    unsigned m3 = h ? W[2 * c + 1][1] : X[2 * c][1];
    u32x4 pw = {m0, m1, m2, m3};
    bf16x8 pf = __builtin_bit_cast(bf16x8, pw);
    bf16x8 vf0 = frag64(Vt, l31, ks * 32 + h * 16);
    bf16x8 vf1 = frag64(Vt, 32 + l31, ks * 32 + h * 16);
    acc0 = __builtin_amdgcn_mfma_f32_32x32x16_bf16(pf, vf0, acc0, 0, 0, 0);
    acc1 = __builtin_amdgcn_mfma_f32_32x32x16_bf16(pf, vf1, acc1, 0, 0, 0);
  }
  __builtin_amdgcn_s_setprio(0);
}

__global__ __launch_bounds__(512, 4) void attn_kernel(
    const bf16* __restrict__ q, const bf16* __restrict__ k,
    const bf16* __restrict__ vt, bf16* __restrict__ att)
{
  __shared__ __align__(16) char pool[65536];
  const int t = threadIdx.x;
  const int w = t >> 6;
  const int wsub = w & 3;
  const int par = w >> 2;
  const int lane = t & 63;
  const int l31 = lane & 31;
  const int h = lane >> 5;

  const int idx = blockIdx.x;
  const int half = idx >> 8;
  const int sub = idx & 255;
  const int bh = sub & 31;
  const int j = half ? (sub >> 5) : (15 - (sub >> 5));

  const int strip = 2 * j + (wsub >> 1);
  const int myN = strip + 1;
  const int npair = j + 1;
  const int q0w = j * 128 + wsub * 32;
  const int qloc = (wsub & 1) * 32 + l31;

  const bf16* qb = q + (size_t)bh * SEQ * HD;
  const char* kbB = (const char*)(k + (size_t)bh * SEQ * HD);
  const char* vbB = (const char*)(vt + (size_t)bh * HD * SEQ);

  bf16x8 qf[4];
#pragma unroll
  for (int s = 0; s < 4; ++s)
    qf[s] = *reinterpret_cast<const bf16x8*>(qb + (size_t)(q0w + l31) * HD + s * 16 + h * 8);

  f32x16 acc0 = {}, acc1 = {};
  float mrow = -1e30f, lrow = 0.f;

  stage512(kbB, 128, 0, pool + 0 * 8192, t);
  stage512(vbB, 4096, 0, pool + 32768 + 0 * 8192, t);
  stage512(kbB + 8192, 128, 0, pool + 1 * 8192, t);
  stage512(vbB, 4096, 128, pool + 32768 + 1 * 8192, t);
  if (npair > 1) {
    stage512(kbB + 2 * 8192, 128, 0, pool + 2 * 8192, t);
    stage512(vbB, 4096, 2 * 128, pool + 32768 + 2 * 8192, t);
    stage512(kbB + 3 * 8192, 128, 0, pool + 3 * 8192, t);
    stage512(vbB, 4096, 3 * 128, pool + 32768 + 3 * 8192, t);
  }

  for (int u = 0; u < npair; ++u) {
    if (u < npair - 1) {
      asm volatile("s_waitcnt vmcnt(4)" ::: "memory");
    } else {
      asm volatile("s_waitcnt vmcnt(0)" ::: "memory");
    }
    __builtin_amdgcn_sched_barrier(0);
    __builtin_amdgcn_s_barrier();

    const int tt = 2 * u + par;
    if (tt < myN)
      tile_step(pool + (tt & 3) * 8192, pool + 32768 + (tt & 3) * 8192, qf,
                acc0, acc1, mrow, lrow, l31, h, tt == strip, qloc);

    __builtin_amdgcn_s_barrier();
    __builtin_amdgcn_sched_barrier(0);
    if (u + 2 < npair) {
      int nt = 2 * u + 4;
      stage512(kbB + (size_t)nt * 8192, 128, 0, pool + (nt & 3) * 8192, t);
      stage512(vbB, 4096, nt * 128, pool + 32768 + (nt & 3) * 8192, t);
      stage512(kbB + (size_t)(nt + 1) * 8192, 128, 0, pool + ((nt + 1) & 3) * 8192, t);
      stage512(vbB, 4096, (nt + 1) * 128, pool + 32768 + ((nt + 1) & 3) * 8192, t);
    }
  }

  float* mb = (float*)pool;
  float* reg = mb + wsub * (34 * 64);
  if (par == 1) {
#pragma unroll
    for (int i = 0; i < 16; ++i) reg[i * 64 + lane] = acc0[i];
#pragma unroll
    for (int i = 0; i < 16; ++i) reg[(16 + i) * 64 + lane] = acc1[i];
    reg[32 * 64 + lane] = mrow;
    reg[33 * 64 + lane] = lrow;
  }
  __syncthreads();
  if (par == 0) {
    float mB = reg[32 * 64 + lane];
    float lB = reg[33 * 64 + lane];
    float mM = fmaxf(mrow, mB);
    float alpha = exp2f(mrow - mM);
    float beta  = exp2f(mB - mM);
    float linv = 1.0f / (alpha * lrow + beta * lB);
#pragma unroll
    for (int rg = 0; rg < 16; ++rg) {
      int rs = (rg & 3) + 8 * (rg >> 2) + 4 * h;
      float a  = __shfl(alpha, rs);
      float b  = __shfl(beta, rs);
      float li = __shfl(linv, rs);
      float o0 = (a * acc0[rg] + b * reg[rg * 64 + lane]) * li;
      float o1 = (a * acc1[rg] + b * reg[(16 + rg) * 64 + lane]) * li;
      size_t base = ((size_t)bh * SEQ + q0w + rs) * HD;
      att[base + l31]      = (bf16)o0;
      att[base + 32 + l31] = (bf16)o1;
    }
  }
}

extern "C" void kernel_launch(void* const* d_in, const int* in_sizes, int n_in,
                              void* d_out, int out_size, void* d_ws, size_t ws_size,
                              hipStream_t stream) {
  const float* x  = (const float*)d_in[0];
  const int* pos  = (const int*)d_in[1];
  const float* Wq = (const float*)d_in[2];
  const float* Wk = (const float*)d_in[3];
  const float* Wv = (const float*)d_in[4];
  const float* Wo = (const float*)d_in[5];
  float* out = (float*)d_out;

  char* p = (char*)d_ws;
  bf16* xb   = (bf16*)p; p += (size_t)MTOT * DM * 2;
  bf16* wqb  = (bf16*)p; p += (size_t)DM * DM * 2;
  bf16* wkb  = (bf16*)p; p += (size_t)DM * DM * 2;
  bf16* wvb  = (bf16*)p; p += (size_t)DM * DM * 2;
  bf16* wob  = (bf16*)p; p += (size_t)DM * DM * 2;
  bf16* qb   = (bf16*)p; p += (size_t)MTOT * DM * 2;
  bf16* kb   = (bf16*)p; p += (size_t)MTOT * DM * 2;
  bf16* vtb  = (bf16*)p; p += (size_t)MTOT * DM * 2;
  bf16* attb = (bf16*)p; p += (size_t)MTOT * DM * 2;
  float2* tab = (float2*)p; p += (size_t)MTOT * 32 * sizeof(float2);
  (void)wkb; (void)wvb;

  cvt_kernel<<<(MTOT * DM / 4 + 255) / 256, 256, 0, stream>>>(x, xb, MTOT * DM / 4);
  cvt4_kernel<<<(4 * 262144 + 255) / 256, 256, 0, stream>>>(Wq, Wk, Wv, Wo, wqb);
  rope_tab_kernel<<<(MTOT * 32 + 255) / 256, 256, 0, stream>>>(pos, tab);

  gemm_qkv<<<dim3(12, MTOT / 256), 512, 0, stream>>>(xb, wqb, qb, kb, vtb, tab);

  attn_kernel<<<512, 512, 0, stream>>>(qb, kb, vtb, attb);

  gemm_out<<<dim3(DM / 128, MTOT / 128), 256, 0, stream>>>(attb, wob, out);
}

// Round 9
// 126.557 us; speedup vs baseline: 1.4286x; 1.1103x over previous
//
#include <hip/hip_runtime.h>
#include <hip/hip_bf16.h>

typedef __bf16 bf16;
typedef __bf16 bf16x4 __attribute__((ext_vector_type(4)));
typedef __bf16 bf16x8 __attribute__((ext_vector_type(8)));
typedef float f32x4 __attribute__((ext_vector_type(4)));
typedef float f32x16 __attribute__((ext_vector_type(16)));
typedef unsigned int u32x4 __attribute__((ext_vector_type(4)));

#define NH 16
#define HD 64
#define SEQ 2048
#define DM 1024
#define MTOT 4096   // B*S

__device__ __forceinline__ void gload_lds16(const void* g, void* l) {
  __builtin_amdgcn_global_load_lds(
      (const __attribute__((address_space(1))) void*)g,
      (__attribute__((address_space(3))) void*)l, 16, 0, 0);
}

// ---------------- fp32 -> bf16 conversion (vectorized) ----------------
__global__ void cvt_kernel(const float* __restrict__ in, bf16* __restrict__ out, int n4) {
  int i = blockIdx.x * blockDim.x + threadIdx.x;
  if (i >= n4) return;
  float4 v = reinterpret_cast<const float4*>(in)[i];
  bf16x4 o;
  o[0] = (bf16)v.x; o[1] = (bf16)v.y; o[2] = (bf16)v.z; o[3] = (bf16)v.w;
  *reinterpret_cast<bf16x4*>(out + (size_t)i * 4) = o;
}

// 4 weight matrices (1M elems each) -> contiguous bf16 out
__global__ void cvt4_kernel(const float* __restrict__ w0, const float* __restrict__ w1,
                            const float* __restrict__ w2, const float* __restrict__ w3,
                            bf16* __restrict__ out) {
  int i = blockIdx.x * blockDim.x + threadIdx.x;   // 0 .. 4*262144-1
  int seg = i >> 18;
  int j = i & 262143;
  const float* src = seg == 0 ? w0 : seg == 1 ? w1 : seg == 2 ? w2 : w3;
  float4 v = reinterpret_cast<const float4*>(src)[j];
  bf16x4 o;
  o[0] = (bf16)v.x; o[1] = (bf16)v.y; o[2] = (bf16)v.z; o[3] = (bf16)v.w;
  *reinterpret_cast<bf16x4*>(out + ((size_t)seg << 20) + (size_t)j * 4) = o;
}

// ---------------- RoPE cos/sin table: tab[m][i2] = (cos, sin) ----------------
__global__ void rope_tab_kernel(const int* __restrict__ pos, float2* __restrict__ tab) {
  int i = blockIdx.x * blockDim.x + threadIdx.x;
  if (i >= MTOT * 32) return;
  int m = i >> 5, i2 = i & 31;
  float pf = (float)pos[m];
  float inv = 1.0f / powf(10000.0f, (float)(2 * i2) * (1.0f / 64.0f));
  float a = pf * inv;
  tab[i] = make_float2(cosf(a), sinf(a));
}

// ---------------- fused QKV projection GEMM, 256x256 tile, BK=64, 8-PHASE ----------------
// grid (12, 16): proj = x>>2, n0 = (x&3)*256 within proj. 512 threads = 8 waves (2M x 4N).
// LDS regions [A|B][tile parity][kk-half]: 256 rows x 32 bf16 (64 B) contiguous = 16 KB each,
// total 128 KB. Source pre-swizzle cb ^= ((r>>1)&3)<<4 -> frag ds_read_b128 2-way (free).
// 8 phases / 2 K-tiles: each phase {ds_read 4|8, stage 1 half (2 gload_lds),
// vmcnt(8) at odd phases, barrier, lgkmcnt(0), setprio, 16 MFMA, setprio, barrier}.
// Ledger: region staged at phase p is first read >= 5 phases later, certified by the
// vmcnt(8)+barrier of the preceding odd phase; overwrite of a region happens only after
// the closing barrier of its last reader phase. Prologue: 12 loads + vmcnt(4).
// Epilogue iteration (tiles 14,15): drain vmcnt 8 -> 4 -> 0.
__global__ __launch_bounds__(512, 2) void gemm_qkv(
    const bf16* __restrict__ A, const bf16* __restrict__ wAll,
    bf16* __restrict__ outq, bf16* __restrict__ outk, bf16* __restrict__ outv,
    const float2* __restrict__ tab)
{
  __shared__ bf16 ABlds[2][2][2][8192];   // [A=0/B=1][parity][kk] 256x32 bf16 = 16 KB
  const int t = threadIdx.x;
  const int w = t >> 6;
  const int wm = w >> 2, wn = w & 3;
  const int lane = t & 63;
  const int lr = lane & 15;
  const int lg = lane >> 4;
  const int m0 = blockIdx.y * 256;
  const int proj = blockIdx.x >> 2;
  const int n0l = (blockIdx.x & 3) * 256;
  const char* Asrc = (const char*)A + (size_t)m0 * 2048;
  const char* Bsrc = (const char*)(wAll + ((size_t)proj << 20) + (size_t)n0l * DM);

  f32x4 acc[8][4] = {};
  bf16x8 bfr[4];

#define REG(AB_, PAR_, KK_) ((char*)ABlds + (((AB_)*4 + (PAR_)*2 + (KK_)) * 16384))

#define STAGE_HALF(AB_, T_, KK_)                                                   \
  {                                                                                \
    const char* gb_ = (AB_) ? Bsrc : Asrc;                                         \
    char* lb_ = REG(AB_, (T_) & 1, KK_);                                           \
    _Pragma("unroll")                                                              \
    for (int p_ = 0; p_ < 2; ++p_) {                                               \
      int o_ = (p_ * 512 + t) * 16;                                                \
      int r_ = o_ >> 6, c_ = o_ & 63;                                              \
      int cs_ = c_ ^ (((r_ >> 1) & 3) << 4);                                       \
      gload_lds16(gb_ + (size_t)r_ * 2048 + (T_) * 128 + (KK_) * 64 + cs_,         \
                  lb_ + o_);                                                       \
    }                                                                              \
  }

#define RDFRAG(DST, REGP, ROW)                                                     \
  {                                                                                \
    int row_ = (ROW);                                                              \
    int cb_ = (lg * 16) ^ (((row_ >> 1) & 3) << 4);                                \
    DST = *reinterpret_cast<const bf16x8*>((REGP) + row_ * 64 + cb_);              \
  }

// PHASE(PAR, KK, MH, DOSTAGE, S_AB, S_T, S_KK, VM)
#define PHASE(PAR, KK, MH, DOSTAGE, S_AB, S_T, S_KK, VM)                           \
  {                                                                                \
    bf16x8 af_[4];                                                                 \
    const char* areg_ = REG(0, PAR, KK);                                           \
    _Pragma("unroll")                                                              \
    for (int f_ = 0; f_ < 4; ++f_)                                                 \
      RDFRAG(af_[f_], areg_, wm * 128 + (MH) * 64 + f_ * 16 + lr);                 \
    if ((MH) == 0) {                                                               \
      const char* breg_ = REG(1, PAR, KK);                                         \
      _Pragma("unroll")                                                            \
      for (int j_ = 0; j_ < 4; ++j_)                                               \
        RDFRAG(bfr[j_], breg_, wn * 64 + j_ * 16 + lr);                            \
    }                                                                              \
    if (DOSTAGE) STAGE_HALF(S_AB, S_T, S_KK);                                      \
    if ((VM) == 8) asm volatile("s_waitcnt vmcnt(8)" ::: "memory");                \
    if ((VM) == 4) asm volatile("s_waitcnt vmcnt(4)" ::: "memory");                \
    if ((VM) == 0) asm volatile("s_waitcnt vmcnt(0)" ::: "memory");                \
    __builtin_amdgcn_sched_barrier(0);                                             \
    __builtin_amdgcn_s_barrier();                                                  \
    asm volatile("s_waitcnt lgkmcnt(0)" ::: "memory");                             \
    __builtin_amdgcn_sched_barrier(0);                                             \
    __builtin_amdgcn_s_setprio(1);                                                 \
    _Pragma("unroll")                                                              \
    for (int f_ = 0; f_ < 4; ++f_)                                                 \
      _Pragma("unroll")                                                            \
      for (int j_ = 0; j_ < 4; ++j_)                                               \
        acc[(MH) * 4 + f_][j_] = __builtin_amdgcn_mfma_f32_16x16x32_bf16(          \
            af_[f_], bfr[j_], acc[(MH) * 4 + f_][j_], 0, 0, 0);                    \
    __builtin_amdgcn_s_setprio(0);                                                 \
    __builtin_amdgcn_s_barrier();                                                  \
  }

  // prologue: tile 0 fully + AK0,BK0 of tile 1 (12 loads); vmcnt(4) certifies tile 0
  STAGE_HALF(0, 0, 0); STAGE_HALF(1, 0, 0);
  STAGE_HALF(0, 0, 1); STAGE_HALF(1, 0, 1);
  STAGE_HALF(0, 1, 0); STAGE_HALF(1, 1, 0);
  asm volatile("s_waitcnt vmcnt(4)" ::: "memory");
  __builtin_amdgcn_sched_barrier(0);
  __builtin_amdgcn_s_barrier();

  for (int i = 0; i < 7; ++i) {
    const int t1 = 2 * i + 1, t2 = 2 * i + 2, t3 = 2 * i + 3;
    PHASE(0, 0, 0, 1, 0, t1, 1, -1);   // read tile2i kk0 mh0 ; stage AK1(2i+1)
    PHASE(0, 0, 1, 1, 1, t1, 1,  8);   //                      stage BK1(2i+1)
    PHASE(0, 1, 0, 1, 0, t2, 0, -1);   // read tile2i kk1     ; stage AK0(2i+2)
    PHASE(0, 1, 1, 1, 1, t2, 0,  8);   //                      stage BK0(2i+2)
    PHASE(1, 0, 0, 1, 0, t2, 1, -1);   // read tile2i+1 kk0   ; stage AK1(2i+2)
    PHASE(1, 0, 1, 1, 1, t2, 1,  8);   //                      stage BK1(2i+2)
    PHASE(1, 1, 0, 1, 0, t3, 0, -1);   // read tile2i+1 kk1   ; stage AK0(2i+3)
    PHASE(1, 1, 1, 1, 1, t3, 0,  8);   //                      stage BK0(2i+3)
  }
  // epilogue iteration: tiles 14,15 ; stage only AK1,BK1(15); drain 8 -> 4 -> 0
  PHASE(0, 0, 0, 1, 0, 15, 1, -1);
  PHASE(0, 0, 1, 1, 1, 15, 1,  8);
  PHASE(0, 1, 0, 0, 0, 0, 0, -1);
  PHASE(0, 1, 1, 0, 0, 0, 0,  4);
  PHASE(1, 0, 0, 0, 0, 0, 0, -1);
  PHASE(1, 0, 1, 0, 0, 0, 0,  0);
  PHASE(1, 1, 0, 0, 0, 0, 0, -1);
  PHASE(1, 1, 1, 0, 0, 0, 0, -1);

#undef PHASE
#undef RDFRAG
#undef STAGE_HALF
#undef REG

  if (proj < 2) {
    bf16* outb = proj ? outk : outq;
#pragma unroll
    for (int j = 0; j < 4; ++j) {
      int nl = n0l + wn * 64 + j * 16 + lr;
      int h = nl >> 6, d = nl & 63;
      int i2 = d >> 1;
      bool odd = d & 1;
#pragma unroll
      for (int i = 0; i < 8; ++i) {
#pragma unroll
        for (int rr = 0; rr < 4; ++rr) {
          int m = m0 + wm * 128 + i * 16 + lg * 4 + rr;
          float v = acc[i][j][rr];
          float o = __shfl_xor(v, 1);
          float2 cs = tab[(m << 5) + i2];
          float res = odd ? (v * cs.x + o * cs.y) : (v * cs.x - o * cs.y);
          if (proj == 0) res *= 0.125f * 1.44269504f;   // 1/sqrt(hd) * log2(e)
          outb[((size_t)((m >> 11) * NH + h) * SEQ + (m & 2047)) * HD + d] = (bf16)res;
        }
      }
    }
  } else {
#pragma unroll
    for (int j = 0; j < 4; ++j) {
      int nl = n0l + wn * 64 + j * 16 + lr;
      int h = nl >> 6, d = nl & 63;
#pragma unroll
      for (int i = 0; i < 8; ++i) {
#pragma unroll
        for (int rr = 0; rr < 4; ++rr) {
          int m = m0 + wm * 128 + i * 16 + lg * 4 + rr;
          outv[((size_t)((m >> 11) * NH + h) * HD + d) * SEQ + (m & 2047)] = (bf16)acc[i][j][rr];
        }
      }
    }
  }
}

// ---------------- output projection GEMM (A from att [B,H,S,hd]) ----------------
// 128x128 tile, BK=32, 4 waves, counted-vmcnt ring (unchanged from r8).
__global__ __launch_bounds__(256) void gemm_out(
    const bf16* __restrict__ A, const bf16* __restrict__ Bw, float* __restrict__ outf)
{
  __shared__ bf16 As[2][128 * 32];
  __shared__ bf16 Bs[2][128 * 32];
  const int t = threadIdx.x;
  const int w = t >> 6;
  const int lane = t & 63;
  const int lr = lane & 15;
  const int lg = lane >> 4;
  const int m0 = blockIdx.y * 128;
  const int n0 = blockIdx.x * 128;
  const int wr = w >> 1, wc = w & 1;
  const char* Bb = (const char*)Bw;

  f32x4 acc[4][4] = {};

#define STAGE_OUT(KT, SLOT)                                                            \
  {                                                                                    \
    _Pragma("unroll")                                                                  \
    for (int p = 0; p < 2; ++p) {                                                      \
      int o = (p * 256 + t) * 16;                                                      \
      int r = o >> 6, cb = o & 63;                                                     \
      int m = m0 + r;                                                                  \
      const char* ga = (const char*)A +                                                \
          ((((size_t)(m >> 11) * NH + ((KT) >> 1)) * SEQ + (m & 2047)) * HD +          \
           ((KT) & 1) * 32) * 2 + cb;                                                  \
      gload_lds16(ga, (char*)As[SLOT] + o);                                            \
    }                                                                                  \
    _Pragma("unroll")                                                                  \
    for (int p = 0; p < 2; ++p) {                                                      \
      int o = (p * 256 + t) * 16;                                                      \
      int r = o >> 6, cb = o & 63;                                                     \
      gload_lds16(Bb + (size_t)(n0 + r) * 2048 + (KT) * 64 + cb, (char*)Bs[SLOT] + o); \
    }                                                                                  \
  }

  STAGE_OUT(0, 0);
  for (int kt = 0; kt < 32; ++kt) {
    if (kt + 1 < 32) {
      STAGE_OUT(kt + 1, (kt + 1) & 1);
      asm volatile("s_waitcnt vmcnt(4)" ::: "memory");
    } else {
      asm volatile("s_waitcnt vmcnt(0)" ::: "memory");
    }
    __builtin_amdgcn_sched_barrier(0);
    __builtin_amdgcn_s_barrier();

    const bf16* Abuf = As[kt & 1];
    const bf16* Bbuf = Bs[kt & 1];
    bf16x8 af[4], bfr[4];
#pragma unroll
    for (int f = 0; f < 4; ++f) {
      af[f]  = *reinterpret_cast<const bf16x8*>(Abuf + (wr * 64 + f * 16 + lr) * 32 + lg * 8);
      bfr[f] = *reinterpret_cast<const bf16x8*>(Bbuf + (wc * 64 + f * 16 + lr) * 32 + lg * 8);
    }
    __builtin_amdgcn_s_setprio(1);
#pragma unroll
    for (int i = 0; i < 4; ++i)
#pragma unroll
      for (int j = 0; j < 4; ++j)
        acc[i][j] = __builtin_amdgcn_mfma_f32_16x16x32_bf16(af[i], bfr[j], acc[i][j], 0, 0, 0);
    __builtin_amdgcn_s_setprio(0);
    __builtin_amdgcn_s_barrier();
  }

#pragma unroll
  for (int j = 0; j < 4; ++j) {
    int n = n0 + wc * 64 + j * 16 + lr;
#pragma unroll
    for (int i = 0; i < 4; ++i) {
#pragma unroll
      for (int rr = 0; rr < 4; ++rr) {
        int m = m0 + wr * 64 + i * 16 + lg * 4 + rr;
        outf[(size_t)m * DM + n] = acc[i][j][rr];
      }
    }
  }
#undef STAGE_OUT
}

// ---------------- flash attention (unchanged from r7/r8) ----------------
__device__ __forceinline__ void stage512(const char* gRow0, size_t rowStrideB, int colByte0,
                                         char* lds, int t) {
  int o = t * 16;
  int r = o >> 7;
  int cb = o & 127;
  int cbs = cb ^ ((r & 7) << 4);
  gload_lds16(gRow0 + (size_t)r * rowStrideB + colByte0 + cbs, lds + o);
}

__device__ __forceinline__ bf16x8 frag64(const char* tile, int row, int colByte) {
  int b = row * 128 + (colByte ^ ((row & 7) << 4));
  return *reinterpret_cast<const bf16x8*>(tile + b);
}

__device__ __forceinline__ unsigned packw(float a, float b) {
  unsigned short la = __builtin_bit_cast(unsigned short, (bf16)a);
  unsigned short lb = __builtin_bit_cast(unsigned short, (bf16)b);
  return (unsigned)la | ((unsigned)lb << 16);
}

__device__ __forceinline__ void tile_step(const char* Kt, const char* Vt,
                                          const bf16x8* qf,
                                          f32x16& acc0, f32x16& acc1,
                                          float& mrow, float& lrow,
                                          int l31, int h, bool domask, int qloc) {
  f32x16 s0 = {}, s1 = {};
  __builtin_amdgcn_s_setprio(1);
#pragma unroll
  for (int s = 0; s < 4; ++s) {
    bf16x8 kf0 = frag64(Kt, l31, s * 32 + h * 16);
    bf16x8 kf1 = frag64(Kt, 32 + l31, s * 32 + h * 16);
    s0 = __builtin_amdgcn_mfma_f32_32x32x16_bf16(kf0, qf[s], s0, 0, 0, 0);
    s1 = __builtin_amdgcn_mfma_f32_32x32x16_bf16(kf1, qf[s], s1, 0, 0, 0);
  }
  __builtin_amdgcn_s_setprio(0);
  if (domask) {
#pragma unroll
    for (int reg = 0; reg < 16; ++reg) {
      int ro = (reg & 3) + 8 * (reg >> 2) + 4 * h;
      if (ro > qloc) s0[reg] = -1e30f;
      if (ro + 32 > qloc) s1[reg] = -1e30f;
    }
  }
  float tm[16];
#pragma unroll
  for (int i = 0; i < 16; ++i) tm[i] = fmaxf(s0[i], s1[i]);
#pragma unroll
  for (int off = 8; off >= 1; off >>= 1)
#pragma unroll
    for (int i = 0; i < off; ++i) tm[i] = fmaxf(tm[i], tm[i + off]);
  float rmax = fmaxf(tm[0], __shfl_xor(tm[0], 32));
  bool need = __any(rmax > mrow + 11.5f);
  if (need) {
    float mnew = fmaxf(mrow, rmax);
    float osc = exp2f(mrow - mnew);
#pragma unroll
    for (int reg = 0; reg < 16; ++reg) {
      int rs = (reg & 3) + 8 * (reg >> 2) + 4 * h;
      float o = __shfl(osc, rs);
      acc0[reg] *= o;
      acc1[reg] *= o;
    }
    lrow *= osc;
    mrow = mnew;
  }
#pragma unroll
  for (int i = 0; i < 16; ++i) {
    s0[i] = exp2f(s0[i] - mrow);
    s1[i] = exp2f(s1[i] - mrow);
  }
  float ts[16];
#pragma unroll
  for (int i = 0; i < 16; ++i) ts[i] = s0[i] + s1[i];
#pragma unroll
  for (int off = 8; off >= 1; off >>= 1)
#pragma unroll
    for (int i = 0; i < off; ++i) ts[i] += ts[i + off];
  lrow += ts[0] + __shfl_xor(ts[0], 32);

  unsigned W0[4][2], W1[4][2], X0[4][2], X1[4][2];
#pragma unroll
  for (int sp = 0; sp < 4; ++sp)
#pragma unroll
    for (int u = 0; u < 2; ++u) {
      W0[sp][u] = packw(s0[sp * 4 + 2 * u], s0[sp * 4 + 2 * u + 1]);
      W1[sp][u] = packw(s1[sp * 4 + 2 * u], s1[sp * 4 + 2 * u + 1]);
    }
#pragma unroll
  for (int sp = 0; sp < 4; ++sp)
#pragma unroll
    for (int u = 0; u < 2; ++u) {
      X0[sp][u] = (unsigned)__shfl_xor((int)W0[sp][u], 32);
      X1[sp][u] = (unsigned)__shfl_xor((int)W1[sp][u], 32);
    }
  __builtin_amdgcn_s_setprio(1);
#pragma unroll
  for (int ks = 0; ks < 4; ++ks) {
    const unsigned (*W)[2] = (ks < 2) ? W0 : W1;
    const unsigned (*X)[2] = (ks < 2) ? X0 : X1;
    const int c = ks & 1;
    unsigned m0 = h ? X[2 * c + 1][0] : W[2 * c][0];
    unsigned m1 = h ? X[2 * c + 1][1] : W[2 * c][1];
    unsigned m2 = h ? W[2 * c + 1][0] : X[2 * c][0];
    unsigned m3 = h ? W[2 * c + 1][1] : X[2 * c][1];
    u32x4 pw = {m0, m1, m2, m3};
    bf16x8 pf = __builtin_bit_cast(bf16x8, pw);
    bf16x8 vf0 = frag64(Vt, l31, ks * 32 + h * 16);
    bf16x8 vf1 = frag64(Vt, 32 + l31, ks * 32 + h * 16);
    acc0 = __builtin_amdgcn_mfma_f32_32x32x16_bf16(pf, vf0, acc0, 0, 0, 0);
    acc1 = __builtin_amdgcn_mfma_f32_32x32x16_bf16(pf, vf1, acc1, 0, 0, 0);
  }
  __builtin_amdgcn_s_setprio(0);
}

__global__ __launch_bounds__(512, 4) void attn_kernel(
    const bf16* __restrict__ q, const bf16* __restrict__ k,
    const bf16* __restrict__ vt, bf16* __restrict__ att)
{
  __shared__ __align__(16) char pool[65536];
  const int t = threadIdx.x;
  const int w = t >> 6;
  const int wsub = w & 3;
  const int par = w >> 2;
  const int lane = t & 63;
  const int l31 = lane & 31;
  const int h = lane >> 5;

  const int idx = blockIdx.x;
  const int half = idx >> 8;
  const int sub = idx & 255;
  const int bh = sub & 31;
  const int j = half ? (sub >> 5) : (15 - (sub >> 5));

  const int strip = 2 * j + (wsub >> 1);
  const int myN = strip + 1;
  const int npair = j + 1;
  const int q0w = j * 128 + wsub * 32;
  const int qloc = (wsub & 1) * 32 + l31;

  const bf16* qb = q + (size_t)bh * SEQ * HD;
  const char* kbB = (const char*)(k + (size_t)bh * SEQ * HD);
  const char* vbB = (const char*)(vt + (size_t)bh * HD * SEQ);

  bf16x8 qf[4];
#pragma unroll
  for (int s = 0; s < 4; ++s)
    qf[s] = *reinterpret_cast<const bf16x8*>(qb + (size_t)(q0w + l31) * HD + s * 16 + h * 8);

  f32x16 acc0 = {}, acc1 = {};
  float mrow = -1e30f, lrow = 0.f;

  stage512(kbB, 128, 0, pool + 0 * 8192, t);
  stage512(vbB, 4096, 0, pool + 32768 + 0 * 8192, t);
  stage512(kbB + 8192, 128, 0, pool + 1 * 8192, t);
  stage512(vbB, 4096, 128, pool + 32768 + 1 * 8192, t);
  if (npair > 1) {
    stage512(kbB + 2 * 8192, 128, 0, pool + 2 * 8192, t);
    stage512(vbB, 4096, 2 * 128, pool + 32768 + 2 * 8192, t);
    stage512(kbB + 3 * 8192, 128, 0, pool + 3 * 8192, t);
    stage512(vbB, 4096, 3 * 128, pool + 32768 + 3 * 8192, t);
  }

  for (int u = 0; u < npair; ++u) {
    if (u < npair - 1) {
      asm volatile("s_waitcnt vmcnt(4)" ::: "memory");
    } else {
      asm volatile("s_waitcnt vmcnt(0)" ::: "memory");
    }
    __builtin_amdgcn_sched_barrier(0);
    __builtin_amdgcn_s_barrier();

    const int tt = 2 * u + par;
    if (tt < myN)
      tile_step(pool + (tt & 3) * 8192, pool + 32768 + (tt & 3) * 8192, qf,
                acc0, acc1, mrow, lrow, l31, h, tt == strip, qloc);

    __builtin_amdgcn_s_barrier();
    __builtin_amdgcn_sched_barrier(0);
    if (u + 2 < npair) {
      int nt = 2 * u + 4;
      stage512(kbB + (size_t)nt * 8192, 128, 0, pool + (nt & 3) * 8192, t);
      stage512(vbB, 4096, nt * 128, pool + 32768 + (nt & 3) * 8192, t);
      stage512(kbB + (size_t)(nt + 1) * 8192, 128, 0, pool + ((nt + 1) & 3) * 8192, t);
      stage512(vbB, 4096, (nt + 1) * 128, pool + 32768 + ((nt + 1) & 3) * 8192, t);
    }
  }

  float* mb = (float*)pool;
  float* reg = mb + wsub * (34 * 64);
  if (par == 1) {
#pragma unroll
    for (int i = 0; i < 16; ++i) reg[i * 64 + lane] = acc0[i];
#pragma unroll
    for (int i = 0; i < 16; ++i) reg[(16 + i) * 64 + lane] = acc1[i];
    reg[32 * 64 + lane] = mrow;
    reg[33 * 64 + lane] = lrow;
  }
  __syncthreads();
  if (par == 0) {
    float mB = reg[32 * 64 + lane];
    float lB = reg[33 * 64 + lane];
    float mM = fmaxf(mrow, mB);
    float alpha = exp2f(mrow - mM);
    float beta  = exp2f(mB - mM);
    float linv = 1.0f / (alpha * lrow + beta * lB);
#pragma unroll
    for (int rg = 0; rg < 16; ++rg) {
      int rs = (rg & 3) + 8 * (rg >> 2) + 4 * h;
      float a  = __shfl(alpha, rs);
      float b  = __shfl(beta, rs);
      float li = __shfl(linv, rs);
      float o0 = (a * acc0[rg] + b * reg[rg * 64 + lane]) * li;
      float o1 = (a * acc1[rg] + b * reg[(16 + rg) * 64 + lane]) * li;
      size_t base = ((size_t)bh * SEQ + q0w + rs) * HD;
      att[base + l31]      = (bf16)o0;
      att[base + 32 + l31] = (bf16)o1;
    }
  }
}

extern "C" void kernel_launch(void* const* d_in, const int* in_sizes, int n_in,
                              void* d_out, int out_size, void* d_ws, size_t ws_size,
                              hipStream_t stream) {
  const float* x  = (const float*)d_in[0];
  const int* pos  = (const int*)d_in[1];
  const float* Wq = (const float*)d_in[2];
  const float* Wk = (const float*)d_in[3];
  const float* Wv = (const float*)d_in[4];
  const float* Wo = (const float*)d_in[5];
  float* out = (float*)d_out;

  char* p = (char*)d_ws;
  bf16* xb   = (bf16*)p; p += (size_t)MTOT * DM * 2;
  bf16* wqb  = (bf16*)p; p += (size_t)DM * DM * 2;
  bf16* wkb  = (bf16*)p; p += (size_t)DM * DM * 2;
  bf16* wvb  = (bf16*)p; p += (size_t)DM * DM * 2;
  bf16* wob  = (bf16*)p; p += (size_t)DM * DM * 2;
  bf16* qb   = (bf16*)p; p += (size_t)MTOT * DM * 2;
  bf16* kb   = (bf16*)p; p += (size_t)MTOT * DM * 2;
  bf16* vtb  = (bf16*)p; p += (size_t)MTOT * DM * 2;
  bf16* attb = (bf16*)p; p += (size_t)MTOT * DM * 2;
  float2* tab = (float2*)p; p += (size_t)MTOT * 32 * sizeof(float2);
  (void)wkb; (void)wvb;

  cvt_kernel<<<(MTOT * DM / 4 + 255) / 256, 256, 0, stream>>>(x, xb, MTOT * DM / 4);
  cvt4_kernel<<<(4 * 262144 + 255) / 256, 256, 0, stream>>>(Wq, Wk, Wv, Wo, wqb);
  rope_tab_kernel<<<(MTOT * 32 + 255) / 256, 256, 0, stream>>>(pos, tab);

  gemm_qkv<<<dim3(12, MTOT / 256), 512, 0, stream>>>(xb, wqb, qb, kb, vtb, tab);

  attn_kernel<<<512, 512, 0, stream>>>(qb, kb, vtb, attb);

  gemm_out<<<dim3(DM / 128, MTOT / 128), 256, 0, stream>>>(attb, wob, out);
}

// Round 11
// 122.026 us; speedup vs baseline: 1.4816x; 1.0371x over previous
//
#include <hip/hip_runtime.h>
#include <hip/hip_bf16.h>

typedef __bf16 bf16;
typedef __bf16 bf16x4 __attribute__((ext_vector_type(4)));
typedef __bf16 bf16x8 __attribute__((ext_vector_type(8)));
typedef float f32x4 __attribute__((ext_vector_type(4)));
typedef float f32x16 __attribute__((ext_vector_type(16)));
typedef unsigned int u32x4 __attribute__((ext_vector_type(4)));

#define NH 16
#define HD 64
#define SEQ 2048
#define DM 1024
#define MTOT 4096   // B*S

__device__ __forceinline__ void gload_lds16(const void* g, void* l) {
  __builtin_amdgcn_global_load_lds(
      (const __attribute__((address_space(1))) void*)g,
      (__attribute__((address_space(3))) void*)l, 16, 0, 0);
}

// ---------------- fused prep: x->bf16, 4 weights->bf16, RoPE table ----------------
__global__ __launch_bounds__(256) void prep_kernel(
    const float* __restrict__ x,
    const float* __restrict__ w0, const float* __restrict__ w1,
    const float* __restrict__ w2, const float* __restrict__ w3,
    const int* __restrict__ pos,
    bf16* __restrict__ xb, bf16* __restrict__ wb, float2* __restrict__ tab)
{
  int i = blockIdx.x * 256 + threadIdx.x;
  if (i < 1048576) {
    float4 v = reinterpret_cast<const float4*>(x)[i];
    bf16x4 o;
    o[0] = (bf16)v.x; o[1] = (bf16)v.y; o[2] = (bf16)v.z; o[3] = (bf16)v.w;
    *reinterpret_cast<bf16x4*>(xb + (size_t)i * 4) = o;
  } else if (i < 2097152) {
    int k = i - 1048576;
    int seg = k >> 18, j = k & 262143;
    const float* src = seg == 0 ? w0 : seg == 1 ? w1 : seg == 2 ? w2 : w3;
    float4 v = reinterpret_cast<const float4*>(src)[j];
    bf16x4 o;
    o[0] = (bf16)v.x; o[1] = (bf16)v.y; o[2] = (bf16)v.z; o[3] = (bf16)v.w;
    *reinterpret_cast<bf16x4*>(wb + ((size_t)seg << 20) + (size_t)j * 4) = o;
  } else if (i < 2097152 + 131072) {
    int k = i - 2097152;
    int m = k >> 5, i2 = k & 31;
    float pf = (float)pos[m];
    float inv = 1.0f / powf(10000.0f, (float)(2 * i2) * (1.0f / 64.0f));
    float a = pf * inv;
    tab[k] = make_float2(cosf(a), sinf(a));
  }
}

// ---------------- fused QKV projection GEMM, 256x256 tile, BK=64, 8-PHASE ----------------
// (unchanged — verified r9) grid (12, 16): proj = x>>2, n0 = (x&3)*256.
__global__ __launch_bounds__(512, 2) void gemm_qkv(
    const bf16* __restrict__ A, const bf16* __restrict__ wAll,
    bf16* __restrict__ outq, bf16* __restrict__ outk, bf16* __restrict__ outv,
    const float2* __restrict__ tab)
{
  __shared__ bf16 ABlds[2][2][2][8192];   // [A=0/B=1][parity][kk] 256x32 bf16 = 16 KB
  const int t = threadIdx.x;
  const int w = t >> 6;
  const int wm = w >> 2, wn = w & 3;
  const int lane = t & 63;
  const int lr = lane & 15;
  const int lg = lane >> 4;
  const int m0 = blockIdx.y * 256;
  const int proj = blockIdx.x >> 2;
  const int n0l = (blockIdx.x & 3) * 256;
  const char* Asrc = (const char*)A + (size_t)m0 * 2048;
  const char* Bsrc = (const char*)(wAll + ((size_t)proj << 20) + (size_t)n0l * DM);

  f32x4 acc[8][4] = {};
  bf16x8 bfr[4];

#define REG(AB_, PAR_, KK_) ((char*)ABlds + (((AB_)*4 + (PAR_)*2 + (KK_)) * 16384))

#define STAGE_HALF(AB_, T_, KK_)                                                   \
  {                                                                                \
    const char* gb_ = (AB_) ? Bsrc : Asrc;                                         \
    char* lb_ = REG(AB_, (T_) & 1, KK_);                                           \
    _Pragma("unroll")                                                              \
    for (int p_ = 0; p_ < 2; ++p_) {                                               \
      int o_ = (p_ * 512 + t) * 16;                                                \
      int r_ = o_ >> 6, c_ = o_ & 63;                                              \
      int cs_ = c_ ^ (((r_ >> 1) & 3) << 4);                                       \
      gload_lds16(gb_ + (size_t)r_ * 2048 + (T_) * 128 + (KK_) * 64 + cs_,         \
                  lb_ + o_);                                                       \
    }                                                                              \
  }

#define RDFRAG(DST, REGP, ROW)                                                     \
  {                                                                                \
    int row_ = (ROW);                                                              \
    int cb_ = (lg * 16) ^ (((row_ >> 1) & 3) << 4);                                \
    DST = *reinterpret_cast<const bf16x8*>((REGP) + row_ * 64 + cb_);              \
  }

#define PHASE(PAR, KK, MH, DOSTAGE, S_AB, S_T, S_KK, VM)                           \
  {                                                                                \
    bf16x8 af_[4];                                                                 \
    const char* areg_ = REG(0, PAR, KK);                                           \
    _Pragma("unroll")                                                              \
    for (int f_ = 0; f_ < 4; ++f_)                                                 \
      RDFRAG(af_[f_], areg_, wm * 128 + (MH) * 64 + f_ * 16 + lr);                 \
    if ((MH) == 0) {                                                               \
      const char* breg_ = REG(1, PAR, KK);                                         \
      _Pragma("unroll")                                                            \
      for (int j_ = 0; j_ < 4; ++j_)                                               \
        RDFRAG(bfr[j_], breg_, wn * 64 + j_ * 16 + lr);                            \
    }                                                                              \
    if (DOSTAGE) STAGE_HALF(S_AB, S_T, S_KK);                                      \
    if ((VM) == 8) asm volatile("s_waitcnt vmcnt(8)" ::: "memory");                \
    if ((VM) == 4) asm volatile("s_waitcnt vmcnt(4)" ::: "memory");                \
    if ((VM) == 0) asm volatile("s_waitcnt vmcnt(0)" ::: "memory");                \
    __builtin_amdgcn_sched_barrier(0);                                             \
    __builtin_amdgcn_s_barrier();                                                  \
    asm volatile("s_waitcnt lgkmcnt(0)" ::: "memory");                             \
    __builtin_amdgcn_sched_barrier(0);                                             \
    __builtin_amdgcn_s_setprio(1);                                                 \
    _Pragma("unroll")                                                              \
    for (int f_ = 0; f_ < 4; ++f_)                                                 \
      _Pragma("unroll")                                                            \
      for (int j_ = 0; j_ < 4; ++j_)                                               \
        acc[(MH) * 4 + f_][j_] = __builtin_amdgcn_mfma_f32_16x16x32_bf16(          \
            af_[f_], bfr[j_], acc[(MH) * 4 + f_][j_], 0, 0, 0);                    \
    __builtin_amdgcn_s_setprio(0);                                                 \
    __builtin_amdgcn_s_barrier();                                                  \
  }

  STAGE_HALF(0, 0, 0); STAGE_HALF(1, 0, 0);
  STAGE_HALF(0, 0, 1); STAGE_HALF(1, 0, 1);
  STAGE_HALF(0, 1, 0); STAGE_HALF(1, 1, 0);
  asm volatile("s_waitcnt vmcnt(4)" ::: "memory");
  __builtin_amdgcn_sched_barrier(0);
  __builtin_amdgcn_s_barrier();

  for (int i = 0; i < 7; ++i) {
    const int t1 = 2 * i + 1, t2 = 2 * i + 2, t3 = 2 * i + 3;
    PHASE(0, 0, 0, 1, 0, t1, 1, -1);
    PHASE(0, 0, 1, 1, 1, t1, 1,  8);
    PHASE(0, 1, 0, 1, 0, t2, 0, -1);
    PHASE(0, 1, 1, 1, 1, t2, 0,  8);
    PHASE(1, 0, 0, 1, 0, t2, 1, -1);
    PHASE(1, 0, 1, 1, 1, t2, 1,  8);
    PHASE(1, 1, 0, 1, 0, t3, 0, -1);
    PHASE(1, 1, 1, 1, 1, t3, 0,  8);
  }
  PHASE(0, 0, 0, 1, 0, 15, 1, -1);
  PHASE(0, 0, 1, 1, 1, 15, 1,  8);
  PHASE(0, 1, 0, 0, 0, 0, 0, -1);
  PHASE(0, 1, 1, 0, 0, 0, 0,  4);
  PHASE(1, 0, 0, 0, 0, 0, 0, -1);
  PHASE(1, 0, 1, 0, 0, 0, 0,  0);
  PHASE(1, 1, 0, 0, 0, 0, 0, -1);
  PHASE(1, 1, 1, 0, 0, 0, 0, -1);

#undef PHASE
#undef RDFRAG
#undef STAGE_HALF
#undef REG

  if (proj < 2) {
    bf16* outb = proj ? outk : outq;
#pragma unroll
    for (int j = 0; j < 4; ++j) {
      int nl = n0l + wn * 64 + j * 16 + lr;
      int h = nl >> 6, d = nl & 63;
      int i2 = d >> 1;
      bool odd = d & 1;
#pragma unroll
      for (int i = 0; i < 8; ++i) {
#pragma unroll
        for (int rr = 0; rr < 4; ++rr) {
          int m = m0 + wm * 128 + i * 16 + lg * 4 + rr;
          float v = acc[i][j][rr];
          float o = __shfl_xor(v, 1);
          float2 cs = tab[(m << 5) + i2];
          float res = odd ? (v * cs.x + o * cs.y) : (v * cs.x - o * cs.y);
          if (proj == 0) res *= 0.125f * 1.44269504f;   // 1/sqrt(hd) * log2(e)
          outb[((size_t)((m >> 11) * NH + h) * SEQ + (m & 2047)) * HD + d] = (bf16)res;
        }
      }
    }
  } else {
#pragma unroll
    for (int j = 0; j < 4; ++j) {
      int nl = n0l + wn * 64 + j * 16 + lr;
      int h = nl >> 6, d = nl & 63;
#pragma unroll
      for (int i = 0; i < 8; ++i) {
#pragma unroll
        for (int rr = 0; rr < 4; ++rr) {
          int m = m0 + wm * 128 + i * 16 + lg * 4 + rr;
          outv[((size_t)((m >> 11) * NH + h) * HD + d) * SEQ + (m & 2047)] = (bf16)acc[i][j][rr];
        }
      }
    }
  }
}

// ---------------- output projection GEMM (unchanged from r8/r9) ----------------
__global__ __launch_bounds__(256) void gemm_out(
    const bf16* __restrict__ A, const bf16* __restrict__ Bw, float* __restrict__ outf)
{
  __shared__ bf16 As[2][128 * 32];
  __shared__ bf16 Bs[2][128 * 32];
  const int t = threadIdx.x;
  const int w = t >> 6;
  const int lane = t & 63;
  const int lr = lane & 15;
  const int lg = lane >> 4;
  const int m0 = blockIdx.y * 128;
  const int n0 = blockIdx.x * 128;
  const int wr = w >> 1, wc = w & 1;
  const char* Bb = (const char*)Bw;

  f32x4 acc[4][4] = {};

#define STAGE_OUT(KT, SLOT)                                                            \
  {                                                                                    \
    _Pragma("unroll")                                                                  \
    for (int p = 0; p < 2; ++p) {                                                      \
      int o = (p * 256 + t) * 16;                                                      \
      int r = o >> 6, cb = o & 63;                                                     \
      int m = m0 + r;                                                                  \
      const char* ga = (const char*)A +                                                \
          ((((size_t)(m >> 11) * NH + ((KT) >> 1)) * SEQ + (m & 2047)) * HD +          \
           ((KT) & 1) * 32) * 2 + cb;                                                  \
      gload_lds16(ga, (char*)As[SLOT] + o);                                            \
    }                                                                                  \
    _Pragma("unroll")                                                                  \
    for (int p = 0; p < 2; ++p) {                                                      \
      int o = (p * 256 + t) * 16;                                                      \
      int r = o >> 6, cb = o & 63;                                                     \
      gload_lds16(Bb + (size_t)(n0 + r) * 2048 + (KT) * 64 + cb, (char*)Bs[SLOT] + o); \
    }                                                                                  \
  }

  STAGE_OUT(0, 0);
  for (int kt = 0; kt < 32; ++kt) {
    if (kt + 1 < 32) {
      STAGE_OUT(kt + 1, (kt + 1) & 1);
      asm volatile("s_waitcnt vmcnt(4)" ::: "memory");
    } else {
      asm volatile("s_waitcnt vmcnt(0)" ::: "memory");
    }
    __builtin_amdgcn_sched_barrier(0);
    __builtin_amdgcn_s_barrier();

    const bf16* Abuf = As[kt & 1];
    const bf16* Bbuf = Bs[kt & 1];
    bf16x8 af[4], bfr[4];
#pragma unroll
    for (int f = 0; f < 4; ++f) {
      af[f]  = *reinterpret_cast<const bf16x8*>(Abuf + (wr * 64 + f * 16 + lr) * 32 + lg * 8);
      bfr[f] = *reinterpret_cast<const bf16x8*>(Bbuf + (wc * 64 + f * 16 + lr) * 32 + lg * 8);
    }
    __builtin_amdgcn_s_setprio(1);
#pragma unroll
    for (int i = 0; i < 4; ++i)
#pragma unroll
      for (int j = 0; j < 4; ++j)
        acc[i][j] = __builtin_amdgcn_mfma_f32_16x16x32_bf16(af[i], bfr[j], acc[i][j], 0, 0, 0);
    __builtin_amdgcn_s_setprio(0);
    __builtin_amdgcn_s_barrier();
  }

#pragma unroll
  for (int j = 0; j < 4; ++j) {
    int n = n0 + wc * 64 + j * 16 + lr;
#pragma unroll
    for (int i = 0; i < 4; ++i) {
#pragma unroll
      for (int rr = 0; rr < 4; ++rr) {
        int m = m0 + wr * 64 + i * 16 + lg * 4 + rr;
        outf[(size_t)m * DM + n] = acc[i][j][rr];
      }
    }
  }
#undef STAGE_OUT
}

// ---------------- flash attention ----------------
// r9 structure; repack via v_permlane32_swap (distinct-valued operands only);
// rmax/rsum via r9-proven __shfl_xor (equal-valued plswap removed — coalescing hazard).
__device__ __forceinline__ void stage512(const char* gRow0, size_t rowStrideB, int colByte0,
                                         char* lds, int t) {
  int o = t * 16;
  int r = o >> 7;
  int cb = o & 127;
  int cbs = cb ^ ((r & 7) << 4);
  gload_lds16(gRow0 + (size_t)r * rowStrideB + colByte0 + cbs, lds + o);
}

__device__ __forceinline__ bf16x8 frag64(const char* tile, int row, int colByte) {
  int b = row * 128 + (colByte ^ ((row & 7) << 4));
  return *reinterpret_cast<const bf16x8*>(tile + b);
}

__device__ __forceinline__ unsigned packw(float a, float b) {
  unsigned short la = __builtin_bit_cast(unsigned short, (bf16)a);
  unsigned short lb = __builtin_bit_cast(unsigned short, (bf16)b);
  return (unsigned)la | ((unsigned)lb << 16);
}

// v_permlane32_swap_b32: DST.row1 <-> SRC.row0  =>  newA=(A_lo,B_lo), newB=(A_hi,B_hi)
// ONLY call with distinct-valued a,b (identical values risk register coalescing).
__device__ __forceinline__ void plswap(unsigned& a, unsigned& b) {
  asm volatile("v_permlane32_swap_b32 %0, %1" : "+v"(a), "+v"(b));
}

__device__ __forceinline__ void tile_step(const char* Kt, const char* Vt,
                                          const bf16x8* qf,
                                          f32x16& acc0, f32x16& acc1,
                                          float& mrow, float& lrow,
                                          int l31, int h, bool domask, int qloc) {
  f32x16 s0 = {}, s1 = {};
  __builtin_amdgcn_s_setprio(1);
#pragma unroll
  for (int s = 0; s < 4; ++s) {
    bf16x8 kf0 = frag64(Kt, l31, s * 32 + h * 16);
    bf16x8 kf1 = frag64(Kt, 32 + l31, s * 32 + h * 16);
    s0 = __builtin_amdgcn_mfma_f32_32x32x16_bf16(kf0, qf[s], s0, 0, 0, 0);
    s1 = __builtin_amdgcn_mfma_f32_32x32x16_bf16(kf1, qf[s], s1, 0, 0, 0);
  }
  __builtin_amdgcn_s_setprio(0);
  if (domask) {
#pragma unroll
    for (int reg = 0; reg < 16; ++reg) {
      int ro = (reg & 3) + 8 * (reg >> 2) + 4 * h;
      if (ro > qloc) s0[reg] = -1e30f;
      if (ro + 32 > qloc) s1[reg] = -1e30f;
    }
  }
  float tm[16];
#pragma unroll
  for (int i = 0; i < 16; ++i) tm[i] = fmaxf(s0[i], s1[i]);
#pragma unroll
  for (int off = 8; off >= 1; off >>= 1)
#pragma unroll
    for (int i = 0; i < off; ++i) tm[i] = fmaxf(tm[i], tm[i + off]);
  float rmax = fmaxf(tm[0], __shfl_xor(tm[0], 32));
  bool need = __any(rmax > mrow + 11.5f);
  if (need) {
    float mnew = fmaxf(mrow, rmax);
    float osc = exp2f(mrow - mnew);
#pragma unroll
    for (int reg = 0; reg < 16; ++reg) {
      int rs = (reg & 3) + 8 * (reg >> 2) + 4 * h;
      float o = __shfl(osc, rs);
      acc0[reg] *= o;
      acc1[reg] *= o;
    }
    lrow *= osc;
    mrow = mnew;
  }
#pragma unroll
  for (int i = 0; i < 16; ++i) {
    s0[i] = exp2f(s0[i] - mrow);
    s1[i] = exp2f(s1[i] - mrow);
  }
  float ts[16];
#pragma unroll
  for (int i = 0; i < 16; ++i) ts[i] = s0[i] + s1[i];
#pragma unroll
  for (int off = 8; off >= 1; off >>= 1)
#pragma unroll
    for (int i = 0; i < off; ++i) ts[i] += ts[i + off];
  lrow += ts[0] + __shfl_xor(ts[0], 32);

  // P -> A-fragment repack via permlane32_swap (T12). Derivation vs r7's proven table:
  // word0: h=0 own W[2c][0], h=1 lane-32's W[2c+1][0]  == newA of plswap(W[2c][0], W[2c+1][0])
  // word2: h=0 lane+32's W[2c][0], h=1 own W[2c+1][0]  == newB of same swap.
  unsigned W0[4][2], W1[4][2];
#pragma unroll
  for (int sp = 0; sp < 4; ++sp)
#pragma unroll
    for (int u = 0; u < 2; ++u) {
      W0[sp][u] = packw(s0[sp * 4 + 2 * u], s0[sp * 4 + 2 * u + 1]);
      W1[sp][u] = packw(s1[sp * 4 + 2 * u], s1[sp * 4 + 2 * u + 1]);
    }
  __builtin_amdgcn_s_setprio(1);
#pragma unroll
  for (int ks = 0; ks < 4; ++ks) {
    const unsigned (*W)[2] = (ks < 2) ? W0 : W1;
    const int c = ks & 1;
    unsigned a0 = W[2 * c][0], b0 = W[2 * c + 1][0];
    unsigned a1 = W[2 * c][1], b1 = W[2 * c + 1][1];
    plswap(a0, b0);
    plswap(a1, b1);
    u32x4 pw = {a0, a1, b0, b1};
    bf16x8 pf = __builtin_bit_cast(bf16x8, pw);
    bf16x8 vf0 = frag64(Vt, l31, ks * 32 + h * 16);
    bf16x8 vf1 = frag64(Vt, 32 + l31, ks * 32 + h * 16);
    acc0 = __builtin_amdgcn_mfma_f32_32x32x16_bf16(pf, vf0, acc0, 0, 0, 0);
    acc1 = __builtin_amdgcn_mfma_f32_32x32x16_bf16(pf, vf1, acc1, 0, 0, 0);
  }
  __builtin_amdgcn_s_setprio(0);
}

__global__ __launch_bounds__(512, 4) void attn_kernel(
    const bf16* __restrict__ q, const bf16* __restrict__ k,
    const bf16* __restrict__ vt, bf16* __restrict__ att)
{
  __shared__ __align__(16) char pool[65536];
  const int t = threadIdx.x;
  const int w = t >> 6;
  const int wsub = w & 3;
  const int par = w >> 2;
  const int lane = t & 63;
  const int l31 = lane & 31;
  const int h = lane >> 5;

  const int idx = blockIdx.x;
  const int half = idx >> 8;
  const int sub = idx & 255;
  const int bh = sub & 31;
  const int j = half ? (sub >> 5) : (15 - (sub >> 5));

  const int strip = 2 * j + (wsub >> 1);
  const int myN = strip + 1;
  const int npair = j + 1;
  const int q0w = j * 128 + wsub * 32;
  const int qloc = (wsub & 1) * 32 + l31;

  const bf16* qb = q + (size_t)bh * SEQ * HD;
  const char* kbB = (const char*)(k + (size_t)bh * SEQ * HD);
  const char* vbB = (const char*)(vt + (size_t)bh * HD * SEQ);

  bf16x8 qf[4];
#pragma unroll
  for (int s = 0; s < 4; ++s)
    qf[s] = *reinterpret_cast<const bf16x8*>(qb + (size_t)(q0w + l31) * HD + s * 16 + h * 8);

  f32x16 acc0 = {}, acc1 = {};
  float mrow = -1e30f, lrow = 0.f;

  stage512(kbB, 128, 0, pool + 0 * 8192, t);
  stage512(vbB, 4096, 0, pool + 32768 + 0 * 8192, t);
  stage512(kbB + 8192, 128, 0, pool + 1 * 8192, t);
  stage512(vbB, 4096, 128, pool + 32768 + 1 * 8192, t);
  if (npair > 1) {
    stage512(kbB + 2 * 8192, 128, 0, pool + 2 * 8192, t);
    stage512(vbB, 4096, 2 * 128, pool + 32768 + 2 * 8192, t);
    stage512(kbB + 3 * 8192, 128, 0, pool + 3 * 8192, t);
    stage512(vbB, 4096, 3 * 128, pool + 32768 + 3 * 8192, t);
  }

  for (int u = 0; u < npair; ++u) {
    if (u < npair - 1) {
      asm volatile("s_waitcnt vmcnt(4)" ::: "memory");
    } else {
      asm volatile("s_waitcnt vmcnt(0)" ::: "memory");
    }
    __builtin_amdgcn_sched_barrier(0);
    __builtin_amdgcn_s_barrier();

    const int tt = 2 * u + par;
    if (tt < myN)
      tile_step(pool + (tt & 3) * 8192, pool + 32768 + (tt & 3) * 8192, qf,
                acc0, acc1, mrow, lrow, l31, h, tt == strip, qloc);

    __builtin_amdgcn_s_barrier();
    __builtin_amdgcn_sched_barrier(0);
    if (u + 2 < npair) {
      int nt = 2 * u + 4;
      stage512(kbB + (size_t)nt * 8192, 128, 0, pool + (nt & 3) * 8192, t);
      stage512(vbB, 4096, nt * 128, pool + 32768 + (nt & 3) * 8192, t);
      stage512(kbB + (size_t)(nt + 1) * 8192, 128, 0, pool + ((nt + 1) & 3) * 8192, t);
      stage512(vbB, 4096, (nt + 1) * 128, pool + 32768 + ((nt + 1) & 3) * 8192, t);
    }
  }

  float* mb = (float*)pool;
  float* reg = mb + wsub * (34 * 64);
  if (par == 1) {
#pragma unroll
    for (int i = 0; i < 16; ++i) reg[i * 64 + lane] = acc0[i];
#pragma unroll
    for (int i = 0; i < 16; ++i) reg[(16 + i) * 64 + lane] = acc1[i];
    reg[32 * 64 + lane] = mrow;
    reg[33 * 64 + lane] = lrow;
  }
  __syncthreads();
  if (par == 0) {
    float mB = reg[32 * 64 + lane];
    float lB = reg[33 * 64 + lane];
    float mM = fmaxf(mrow, mB);
    float alpha = exp2f(mrow - mM);
    float beta  = exp2f(mB - mM);
    float linv = 1.0f / (alpha * lrow + beta * lB);
#pragma unroll
    for (int rg = 0; rg < 16; ++rg) {
      int rs = (rg & 3) + 8 * (rg >> 2) + 4 * h;
      float a  = __shfl(alpha, rs);
      float b  = __shfl(beta, rs);
      float li = __shfl(linv, rs);
      float o0 = (a * acc0[rg] + b * reg[rg * 64 + lane]) * li;
      float o1 = (a * acc1[rg] + b * reg[(16 + rg) * 64 + lane]) * li;
      size_t base = ((size_t)bh * SEQ + q0w + rs) * HD;
      att[base + l31]      = (bf16)o0;
      att[base + 32 + l31] = (bf16)o1;
    }
  }
}

extern "C" void kernel_launch(void* const* d_in, const int* in_sizes, int n_in,
                              void* d_out, int out_size, void* d_ws, size_t ws_size,
                              hipStream_t stream) {
  const float* x  = (const float*)d_in[0];
  const int* pos  = (const int*)d_in[1];
  const float* Wq = (const float*)d_in[2];
  const float* Wk = (const float*)d_in[3];
  const float* Wv = (const float*)d_in[4];
  const float* Wo = (const float*)d_in[5];
  float* out = (float*)d_out;

  char* p = (char*)d_ws;
  bf16* xb   = (bf16*)p; p += (size_t)MTOT * DM * 2;
  bf16* wqb  = (bf16*)p; p += (size_t)DM * DM * 2;
  bf16* wkb  = (bf16*)p; p += (size_t)DM * DM * 2;
  bf16* wvb  = (bf16*)p; p += (size_t)DM * DM * 2;
  bf16* wob  = (bf16*)p; p += (size_t)DM * DM * 2;
  bf16* qb   = (bf16*)p; p += (size_t)MTOT * DM * 2;
  bf16* kb   = (bf16*)p; p += (size_t)MTOT * DM * 2;
  bf16* vtb  = (bf16*)p; p += (size_t)MTOT * DM * 2;
  bf16* attb = (bf16*)p; p += (size_t)MTOT * DM * 2;
  float2* tab = (float2*)p; p += (size_t)MTOT * 32 * sizeof(float2);
  (void)wkb; (void)wvb;

  prep_kernel<<<(2097152 + 131072 + 255) / 256, 256, 0, stream>>>(
      x, Wq, Wk, Wv, Wo, pos, xb, wqb, tab);

  gemm_qkv<<<dim3(12, MTOT / 256), 512, 0, stream>>>(xb, wqb, qb, kb, vtb, tab);

  attn_kernel<<<512, 512, 0, stream>>>(qb, kb, vtb, attb);

  gemm_out<<<dim3(DM / 128, MTOT / 128), 256, 0, stream>>>(attb, wob, out);
}